// Round 8
// baseline (2578.886 us; speedup 1.0000x reference)
//
#include <hip/hip_runtime.h>
#include <hip/hip_cooperative_groups.h>

namespace cg = cooperative_groups;

typedef unsigned short u16;
typedef __attribute__((ext_vector_type(8))) short bf16x8s;
typedef __attribute__((ext_vector_type(4))) float f32x4;

#define DEV static __device__ __forceinline__

DEV float b2f(u16 v) { return __uint_as_float(((unsigned)v) << 16); }
DEV u16 f2b(float f) {
  unsigned u = __float_as_uint(f);
  unsigned r = (u + 0x7fffu + ((u >> 16) & 1u)) >> 16;
  return (u16)r;
}

// async global->LDS, 16B per lane; lds base must be wave-uniform (HW adds lane*16)
#define GLL(gp, lp)                                                            \
  __builtin_amdgcn_global_load_lds(                                            \
      (const __attribute__((address_space(1))) unsigned int*)(gp),             \
      (__attribute__((address_space(3))) unsigned int*)(lp), 16, 0, 0)

#define MFMA __builtin_amdgcn_mfma_f32_16x16x32_bf16

// ---------------- elementwise converts ----------------
__global__ __launch_bounds__(256) void k_f2b(const float* __restrict__ in,
                                             u16* __restrict__ o, long n4) {
  long i = (long)blockIdx.x * 256 + threadIdx.x;
  if (i >= n4) return;
  float4 v = *(const float4*)(in + i * 4);
  u16* d = o + i * 4;
  d[0] = f2b(v.x); d[1] = f2b(v.y); d[2] = f2b(v.z); d[3] = f2b(v.w);
}

// W[k][N] (fp32) -> Wt[n][512] bf16  (K fixed = 512)
__global__ __launch_bounds__(256) void k_wt(const float* __restrict__ W,
                                            u16* __restrict__ Wt, int N) {
  int e = blockIdx.x * 256 + threadIdx.x;  // e < N*512
  int nn = e >> 9, kk = e & 511;
  Wt[e] = f2b(W[(long)kk * N + nn]);
}

// ---------------- 128x128 bf16 NT GEMM (BK=64, global_load_lds, swizzled) ----
template <int MODE>
__global__ __launch_bounds__(256, 2) void k_gemm128(
    const u16* __restrict__ A, const u16* __restrict__ Bm, void* __restrict__ C0,
    void* __restrict__ C1, const float* __restrict__ xres,
    const float* __restrict__ bias, int K) {
  const int nwg = gridDim.x * gridDim.y;
  const int orig = blockIdx.y * gridDim.x + blockIdx.x;
  const int qq = nwg >> 3, rr = nwg & 7;
  const int xcd = orig & 7, loc = orig >> 3;
  const int swz = (xcd < rr ? xcd * (qq + 1) : rr * (qq + 1) + (xcd - rr) * qq) + loc;
  const int m0 = (swz / gridDim.x) << 7, n0 = (swz % gridDim.x) << 7;
  const int t = threadIdx.x, lane = t & 63, w = t >> 6;
  const int wm = (w >> 1) << 6, wn = (w & 1) << 6;
  const int fr = lane & 15, g = lane >> 4;
  __shared__ u16 As[8192];
  __shared__ u16 Bs[8192];
  f32x4 acc[4][4] = {};
  const int srow = t >> 3, scs = t & 7;
  for (int k0 = 0; k0 < K; k0 += 64) {
    __syncthreads();
#pragma unroll
    for (int i = 0; i < 4; ++i) {
      int row = srow + (i << 5), cs = scs;
      GLL(A + (long)(m0 + row) * K + k0 + ((cs ^ (row & 7)) << 3),
          &As[(i << 11) + (w << 9)]);
      GLL(Bm + (long)(n0 + row) * K + k0 + ((cs ^ (row & 7)) << 3),
          &Bs[(i << 11) + (w << 9)]);
    }
    __syncthreads();
#pragma unroll
    for (int ks = 0; ks < 2; ++ks) {
      bf16x8s af[4], bf[4];
#pragma unroll
      for (int fi = 0; fi < 4; ++fi) {
        int row = wm + fi * 16 + fr;
        af[fi] = *(const bf16x8s*)((const char*)As + row * 128 +
                                   (((ks * 4 + g) ^ (row & 7)) << 4));
      }
#pragma unroll
      for (int fj = 0; fj < 4; ++fj) {
        int row = wn + fj * 16 + fr;
        bf[fj] = *(const bf16x8s*)((const char*)Bs + row * 128 +
                                   (((ks * 4 + g) ^ (row & 7)) << 4));
      }
#pragma unroll
      for (int fi = 0; fi < 4; ++fi)
#pragma unroll
        for (int fj = 0; fj < 4; ++fj)
          acc[fi][fj] = MFMA(af[fi], bf[fj], acc[fi][fj], 0, 0, 0);
    }
  }
  const int crow = g << 2;
#pragma unroll
  for (int fi = 0; fi < 4; ++fi)
#pragma unroll
    for (int fj = 0; fj < 4; ++fj)
#pragma unroll
      for (int r = 0; r < 4; ++r) {
        int row = m0 + wm + fi * 16 + crow + r;
        int col = n0 + wn + fj * 16 + fr;
        float v = acc[fi][fj][r];
        if (MODE == 0) {
          int b = row >> 13, n = row & 8191, h = col >> 6, dh = col & 63;
          ((u16*)C0)[((((long)(b * 8 + h)) << 13) + n) * 64 + dh] = f2b(v * 0.125f);
        } else if (MODE == 1) {
          int b = row >> 12, nz = row & 4095;
          if (col < 512) {
            int h = col >> 6, dh = col & 63;
            ((u16*)C0)[((((long)(b * 8 + h)) << 12) + nz) * 64 + dh] = f2b(v);
          } else {
            int c2 = col - 512, h = c2 >> 6, dh = c2 & 63;
            ((u16*)C1)[((((long)(b * 8 + h) * 64 + dh)) << 12) + nz] = f2b(v);
          }
        } else if (MODE == 2) {
          long idx = ((long)row << 9) + col;
          ((float*)C0)[idx] = v + xres[idx] + bias[col];
        }
      }
}

// ---------------- landmarks: mean over groups -> split hi/lo bf16 -----------
__global__ __launch_bounds__(256) void k_landmark(const u16* __restrict__ src,
                                                  u16* __restrict__ hi,
                                                  u16* __restrict__ lo, int ntok,
                                                  int l, float inv) {
  int pidx = blockIdx.x * 4 + (threadIdx.x >> 6);
  int d = threadIdx.x & 63;
  int bh = pidx >> 8, m = pidx & 255;
  const u16* s = src + ((long)bh * ntok + (long)m * l) * 64 + d;
  float sum = 0.f;
  for (int j = 0; j < l; ++j) sum += b2f(s[j * 64]);
  sum *= inv;
  long o = ((long)bh * 256 + m) * 64 + d;
  u16 h = f2b(sum);
  hi[o] = h;
  lo[o] = f2b(sum - b2f(h));
}

// ---------------- sim2 + softmax via split-bf16 MFMA ------------------------
__global__ __launch_bounds__(256, 2) void k_sim2(
    const u16* __restrict__ qlh, const u16* __restrict__ qll,
    const u16* __restrict__ klh, const u16* __restrict__ kll,
    float* __restrict__ attn2, u16* __restrict__ aNhi, u16* __restrict__ aNlo) {
  const int rb = blockIdx.x, bh = blockIdx.y;
  const int t = threadIdx.x, lane = t & 63, w = t >> 6;
  const int fr = lane & 15, g = lane >> 4;
  __shared__ char lds[65536];  // [0,32K) k_land hi ; [32K,64K) k_land lo
  {
    const u16* kh = klh + (long)bh * 16384;
    const u16* kl = kll + (long)bh * 16384;
    int srow8 = lane >> 3, cs7 = lane & 7;
#pragma unroll
    for (int i = 0; i < 8; ++i) {
      int slab = w * 8 + i;
      int krow = slab * 8 + srow8;
      GLL(kh + krow * 64 + ((cs7 ^ (krow & 7)) << 3), lds + slab * 1024);
      GLL(kl + krow * 64 + ((cs7 ^ (krow & 7)) << 3), lds + 32768 + slab * 1024);
    }
  }
  long qoff = ((long)bh * 256 + rb * 64 + w * 16 + fr) * 64;
  bf16x8s qh0 = *(const bf16x8s*)(qlh + qoff + g * 8);
  bf16x8s qh1 = *(const bf16x8s*)(qlh + qoff + 32 + g * 8);
  bf16x8s ql0 = *(const bf16x8s*)(qll + qoff + g * 8);
  bf16x8s ql1 = *(const bf16x8s*)(qll + qoff + 32 + g * 8);
  __syncthreads();
  f32x4 s[16];
#pragma unroll
  for (int c = 0; c < 16; ++c) {
    int j = (c << 4) + fr;
    int o0 = j * 128 + ((g ^ (j & 7)) << 4);
    int o1 = j * 128 + (((4 + g) ^ (j & 7)) << 4);
    bf16x8s kh0 = *(const bf16x8s*)(lds + o0);
    bf16x8s kh1 = *(const bf16x8s*)(lds + o1);
    bf16x8s kl0 = *(const bf16x8s*)(lds + 32768 + o0);
    bf16x8s kl1 = *(const bf16x8s*)(lds + 32768 + o1);
    f32x4 zz = {};
    zz = MFMA(qh0, kh0, zz, 0, 0, 0);
    zz = MFMA(qh1, kh1, zz, 0, 0, 0);
    zz = MFMA(qh0, kl0, zz, 0, 0, 0);
    zz = MFMA(qh1, kl1, zz, 0, 0, 0);
    zz = MFMA(ql0, kh0, zz, 0, 0, 0);
    zz = MFMA(ql1, kh1, zz, 0, 0, 0);
    s[c] = zz;
  }
  float li[4];
#pragma unroll
  for (int r = 0; r < 4; ++r) {
    float m = s[0][r];
#pragma unroll
    for (int c = 1; c < 16; ++c) m = fmaxf(m, s[c][r]);
    m = fmaxf(m, __shfl_xor(m, 1, 64));
    m = fmaxf(m, __shfl_xor(m, 2, 64));
    m = fmaxf(m, __shfl_xor(m, 4, 64));
    m = fmaxf(m, __shfl_xor(m, 8, 64));
    float l = 0.f;
#pragma unroll
    for (int c = 0; c < 16; ++c) {
      float e = __expf(s[c][r] - m);
      s[c][r] = e;
      l += e;
    }
    l += __shfl_xor(l, 1, 64);
    l += __shfl_xor(l, 2, 64);
    l += __shfl_xor(l, 4, 64);
    l += __shfl_xor(l, 8, 64);
    li[r] = 1.f / l;
  }
#pragma unroll
  for (int c = 0; c < 16; ++c)
#pragma unroll
    for (int r = 0; r < 4; ++r) {
      int row = rb * 64 + w * 16 + (g << 2) + r;
      int col = (c << 4) + fr;
      long idx = ((long)bh << 16) + ((long)row << 8) + col;
      float p = s[c][r] * li[r];
      attn2[idx] = p;
      u16 h = f2b(p);
      aNhi[idx] = h;
      aNlo[idx] = f2b(p - b2f(h));
    }
}

__global__ __launch_bounds__(256) void k_colmax(const float* __restrict__ attn2,
                                                unsigned* __restrict__ cmax) {
  int bh = blockIdx.x, j = threadIdx.x, lane = j & 63, w = j >> 6;
  const float* p = attn2 + ((long)bh << 16) + j;
  float s = 0.f;
  for (int m = 0; m < 256; ++m) s += p[m * 256];
  float mx = s;
  for (int o = 1; o < 64; o <<= 1) mx = fmaxf(mx, __shfl_xor(mx, o, 64));
  __shared__ float r1[4];
  if (lane == 0) r1[w] = mx;
  __syncthreads();
  if (j == 0) {
    mx = fmaxf(fmaxf(r1[0], r1[1]), fmaxf(r1[2], r1[3]));
    atomicMax(cmax, __float_as_uint(mx));
  }
}

// ---------------- T1 split-KV partial: (bh, rb, kc of 1024 keys) ------------
__global__ __launch_bounds__(256, 2) void k_t1part(
    const u16* __restrict__ qlb, const u16* __restrict__ kb,
    const u16* __restrict__ vtb, float* __restrict__ opart,
    float* __restrict__ pm_, float* __restrict__ pl_) {
  int orig = blockIdx.x;  // 512 = 32 bh * 4 kc * 4 rb
  int xcd = orig & 7, idx = orig >> 3;
  int p = xcd * 16 + (idx >> 2);  // (bh,kc) pair; 4 rb of a pair share an XCD
  int rb = idx & 3;
  int bh = p >> 2, kc = p & 3;
  const int t = threadIdx.x, lane = t & 63, w = t >> 6;
  const int fr = lane & 15, g = lane >> 4;
  __shared__ char lds[65536];  // [0,32K) K chunk (aliased by P); [32K,64K) V^T
  const u16* qrow = qlb + ((long)bh * 256 + rb * 64 + w * 16 + fr) * 64;
  bf16x8s qa0 = *(const bf16x8s*)(qrow + g * 8);
  bf16x8s qa1 = *(const bf16x8s*)(qrow + 32 + g * 8);
  f32x4 o[4] = {};
  float m[4] = {-3e38f, -3e38f, -3e38f, -3e38f};
  float l[4] = {};
  const long kbase = (long)bh * 262144;
  for (int cc = 0; cc < 4; ++cc) {
    int c0 = kc * 1024 + cc * 256;
    __syncthreads();
#pragma unroll
    for (int i = 0; i < 8; ++i) {
      int seg = (i << 8) + t, row = seg >> 3, cs = seg & 7;
      GLL(kb + kbase + (long)(c0 + row) * 64 + ((cs ^ (row & 7)) << 3),
          lds + (i << 12) + (w << 10));
    }
#pragma unroll
    for (int i = 0; i < 8; ++i) {
      int seg = (i << 8) + t, row = seg >> 5, cs = seg & 31;
      GLL(vtb + kbase + (long)row * 4096 + c0 + ((cs ^ (row & 7)) << 3),
          lds + 32768 + (i << 12) + (w << 10));
    }
    __syncthreads();
    f32x4 s[16];
#pragma unroll
    for (int c = 0; c < 16; ++c) {
      int j = c * 16 + fr;
      bf16x8s b0 = *(const bf16x8s*)(lds + j * 128 + ((g ^ (j & 7)) << 4));
      bf16x8s b1 = *(const bf16x8s*)(lds + j * 128 + (((4 + g) ^ (j & 7)) << 4));
      f32x4 zz = {};
      zz = MFMA(qa0, b0, zz, 0, 0, 0);
      zz = MFMA(qa1, b1, zz, 0, 0, 0);
      s[c] = zz;
    }
    float sc[4];
#pragma unroll
    for (int r = 0; r < 4; ++r) {
      float pm = s[0][r];
#pragma unroll
      for (int c = 1; c < 16; ++c) pm = fmaxf(pm, s[c][r]);
      pm = fmaxf(pm, __shfl_xor(pm, 1, 64));
      pm = fmaxf(pm, __shfl_xor(pm, 2, 64));
      pm = fmaxf(pm, __shfl_xor(pm, 4, 64));
      pm = fmaxf(pm, __shfl_xor(pm, 8, 64));
      float mn = fmaxf(m[r], pm);
      sc[r] = __expf(m[r] - mn);
      m[r] = mn;
    }
#pragma unroll
    for (int r = 0; r < 4; ++r) {
      float su = 0.f;
#pragma unroll
      for (int c = 0; c < 16; ++c) {
        float e = __expf(s[c][r] - m[r]);
        s[c][r] = e;
        su += e;
      }
      su += __shfl_xor(su, 1, 64);
      su += __shfl_xor(su, 2, 64);
      su += __shfl_xor(su, 4, 64);
      su += __shfl_xor(su, 8, 64);
      l[r] = l[r] * sc[r] + su;
    }
#pragma unroll
    for (int d = 0; d < 4; ++d)
#pragma unroll
      for (int r = 0; r < 4; ++r) o[d][r] *= sc[r];
    __syncthreads();
#pragma unroll
    for (int c = 0; c < 16; ++c)
#pragma unroll
      for (int r = 0; r < 4; ++r) {
        int row = (w << 4) + (g << 2) + r;
        int byin = (c << 5) + (fr << 1);
        *(u16*)(lds + row * 512 + (byin ^ ((row & 7) << 4))) = f2b(s[c][r]);
      }
    asm volatile("s_waitcnt lgkmcnt(0)" ::: "memory");
    __builtin_amdgcn_sched_barrier(0);
#pragma unroll
    for (int ss = 0; ss < 8; ++ss) {
      int prow = (w << 4) + fr;
      bf16x8s ap = *(const bf16x8s*)(lds + prow * 512 +
                                     (((ss * 64) + (g << 4)) ^ ((prow & 7) << 4)));
#pragma unroll
      for (int d = 0; d < 4; ++d) {
        int dh = (d << 4) + fr;
        bf16x8s bv = *(const bf16x8s*)(lds + 32768 + dh * 512 +
                                       (((ss * 4 + g) ^ (dh & 7)) << 4));
        o[d] = MFMA(ap, bv, o[d], 0, 0, 0);
      }
    }
  }
  // LDS-transpose o then coalesced float4 writes
  __syncthreads();
  float* lf = (float*)lds;
#pragma unroll
  for (int d = 0; d < 4; ++d)
#pragma unroll
    for (int r = 0; r < 4; ++r)
      lf[((w << 4) + (g << 2) + r) * 76 + (d << 4) + fr] = o[d][r];
  __syncthreads();
  const long pb = (long)(bh * 4 + kc) * 256 + rb * 64;
#pragma unroll
  for (int i = 0; i < 4; ++i) {
    int row = i * 16 + (t >> 4);
    int c4 = (t & 15) << 2;
    float4 v = *(const float4*)&lf[row * 76 + c4];
    *(float4*)&opart[(pb + row) * 64 + c4] = v;
  }
  if (fr == 0) {
#pragma unroll
    for (int r = 0; r < 4; ++r) {
      int lr = (w << 4) + (g << 2) + r;
      pm_[pb + lr] = m[r];
      pl_[pb + lr] = l[r];
    }
  }
}

// ---------------- merge 4 partials -> T1^T split bf16 -----------------------
__global__ __launch_bounds__(256) void k_t1merge(
    const float* __restrict__ opart, const float* __restrict__ pm_,
    const float* __restrict__ pl_, u16* __restrict__ T1thi,
    u16* __restrict__ T1tlo) {
  const int rb = blockIdx.x, bh = blockIdx.y;
  const int t = threadIdx.x;
#pragma unroll
  for (int rp = 0; rp < 4; ++rp) {
    int row = rb * 64 + rp * 16 + (t >> 4);
    int dh4 = (t & 15) << 2;
    float pmv[4], M = -3e38f;
#pragma unroll
    for (int i = 0; i < 4; ++i) {
      pmv[i] = pm_[(long)(bh * 4 + i) * 256 + row];
      M = fmaxf(M, pmv[i]);
    }
    float L = 0.f, wt[4];
#pragma unroll
    for (int i = 0; i < 4; ++i) {
      wt[i] = __expf(pmv[i] - M);
      L += pl_[(long)(bh * 4 + i) * 256 + row] * wt[i];
    }
    float4 acc = {0.f, 0.f, 0.f, 0.f};
#pragma unroll
    for (int i = 0; i < 4; ++i) {
      float4 v = *(const float4*)&opart[((long)(bh * 4 + i) * 256 + row) * 64 + dh4];
      acc.x += v.x * wt[i]; acc.y += v.y * wt[i];
      acc.z += v.z * wt[i]; acc.w += v.w * wt[i];
    }
    float invL = 1.f / L;
    float vv[4] = {acc.x * invL, acc.y * invL, acc.z * invL, acc.w * invL};
#pragma unroll
    for (int e = 0; e < 4; ++e) {
      int dh = dh4 + e;
      long idx = (long)bh * 16384 + (long)dh * 256 + row;
      u16 h = f2b(vv[e]);
      T1thi[idx] = h;
      T1tlo[idx] = f2b(vv[e] - b2f(h));
    }
  }
}

// ---------------- pinv GEMM tile (device fn; NP=1 plain, NP=3 split) --------
template <int NP>
DEV void nn_tile(const u16* __restrict__ Ahi, const u16* __restrict__ Alo,
                 const u16* __restrict__ Bthi, const u16* __restrict__ Btlo,
                 u16* CNhi, u16* CNlo, u16* CThi, u16* CTlo, int Nc, float sab,
                 float sa, float cdiag, int bz, int m0, int n0, u16* lds, int t) {
  const long offA = (long)bz << 16;
  const long offB = (long)bz * ((long)Nc << 8);
  const int lane = t & 63, w = t >> 6;
  const int wm = (w >> 1) << 5, wn = (w & 1) << 5;
  const int fr = lane & 15, g = lane >> 4;
  u16* LAh = lds;
  u16* LAl = lds + 4096;
  u16* LBh = lds + 8192;
  u16* LBl = lds + 12288;
  f32x4 acc[2][2] = {};
  const int srow8 = lane >> 3, cs = lane & 7;
  for (int k0 = 0; k0 < 256; k0 += 64) {
    __syncthreads();
#pragma unroll
    for (int j = 0; j < 2; ++j) {
      int slab = w * 2 + j;
      int row = slab * 8 + srow8;
      long asrc = offA + (long)(m0 + row) * 256 + k0 + ((cs ^ (row & 7)) << 3);
      long bsrc = offB + (long)(n0 + row) * 256 + k0 + ((cs ^ (row & 7)) << 3);
      GLL(Ahi + asrc, LAh + slab * 512);
      GLL(Bthi + bsrc, LBh + slab * 512);
      if (NP == 3) {
        GLL(Alo + asrc, LAl + slab * 512);
        GLL(Btlo + bsrc, LBl + slab * 512);
      }
    }
    __syncthreads();
#pragma unroll
    for (int ks = 0; ks < 2; ++ks) {
      const int ra0 = wm + fr, ra1 = wm + 16 + fr;
      const int rb0 = wn + fr, rb1 = wn + 16 + fr;
#define RD(base, row) \
  (*(const bf16x8s*)((const char*)(base) + (row) * 128 + (((ks * 4 + g) ^ ((row) & 7)) << 4)))
      bf16x8s ah0 = RD(LAh, ra0), ah1 = RD(LAh, ra1);
      bf16x8s bh0 = RD(LBh, rb0), bh1 = RD(LBh, rb1);
      acc[0][0] = MFMA(ah0, bh0, acc[0][0], 0, 0, 0);
      acc[0][1] = MFMA(ah0, bh1, acc[0][1], 0, 0, 0);
      acc[1][0] = MFMA(ah1, bh0, acc[1][0], 0, 0, 0);
      acc[1][1] = MFMA(ah1, bh1, acc[1][1], 0, 0, 0);
      if (NP == 3) {
        bf16x8s al0 = RD(LAl, ra0), al1 = RD(LAl, ra1);
        bf16x8s bl0 = RD(LBl, rb0), bl1 = RD(LBl, rb1);
        acc[0][0] = MFMA(ah0, bl0, acc[0][0], 0, 0, 0);
        acc[0][0] = MFMA(al0, bh0, acc[0][0], 0, 0, 0);
        acc[0][1] = MFMA(ah0, bl1, acc[0][1], 0, 0, 0);
        acc[0][1] = MFMA(al0, bh1, acc[0][1], 0, 0, 0);
        acc[1][0] = MFMA(ah1, bl0, acc[1][0], 0, 0, 0);
        acc[1][0] = MFMA(al1, bh0, acc[1][0], 0, 0, 0);
        acc[1][1] = MFMA(ah1, bl1, acc[1][1], 0, 0, 0);
        acc[1][1] = MFMA(al1, bh1, acc[1][1], 0, 0, 0);
      }
#undef RD
    }
  }
  const int crow = g << 2;
  const long offC = (long)bz * ((long)Nc << 8);
#pragma unroll
  for (int i = 0; i < 2; ++i)
#pragma unroll
    for (int j = 0; j < 2; ++j)
#pragma unroll
      for (int r = 0; r < 4; ++r) {
        int row = m0 + wm + i * 16 + crow + r;
        int col = n0 + wn + j * 16 + fr;
        float v = sab * acc[i][j][r];
        if (sa != 0.f) {
          long ai = offA + ((long)row << 8) + col;
          v += sa * (b2f(Ahi[ai]) + b2f(Alo[ai]));
        }
        if (row == col) v += cdiag;
        if (CNhi) {
          long ci = offC + (long)row * Nc + col;
          u16 h = f2b(v);
          if (CNlo) { CNhi[ci] = h; CNlo[ci] = f2b(v - b2f(h)); }
          else CNhi[ci] = h;
        }
        if (CThi) {
          long ti = offC + ((long)col << 8) + row;
          u16 h = f2b(v);
          CThi[ti] = h;
          if (CTlo) CTlo[ti] = f2b(v - b2f(h));
        }
      }
}

// ---------------- cooperative fused pinv: prep + 6 NS iters + T2 ------------
// grid = 512 blocks (bz 32 x ty 4 x tx 4), 2 blocks/CU co-resident
__global__ __launch_bounds__(256, 2) void k_pinv_coop(
    const u16* __restrict__ aNhi, const u16* __restrict__ aNlo,
    u16* __restrict__ PS, const float* __restrict__ attn2,
    const unsigned* __restrict__ cmax, const u16* __restrict__ T1thi,
    const u16* __restrict__ T1tlo, u16* __restrict__ T2t) {
  __shared__ u16 lds[16384];  // 32KB: GEMM staging / prep transpose buffer
  cg::grid_group grid = cg::this_grid();
  const int bid = blockIdx.x;
  const int bz = bid >> 4, ty = (bid >> 2) & 3, tx = bid & 3;
  const int t = threadIdx.x;
  const int m0 = ty << 6, n0 = tx << 6;
  const long MC = 2097152;
  u16 *zA_N0 = PS,           *zA_N1 = PS + MC,      *zA_T0 = PS + 2 * MC,  *zA_T1 = PS + 3 * MC;
  u16 *zB_N0 = PS + 4 * MC,  *zB_N1 = PS + 5 * MC,  *zB_T0 = PS + 6 * MC,  *zB_T1 = PS + 7 * MC;
  u16 *azN0 = PS + 8 * MC,   *azN1 = PS + 9 * MC,   *azT0 = PS + 10 * MC,  *azT1 = PS + 11 * MC;
  u16 *taT0 = PS + 12 * MC,  *taT1 = PS + 13 * MC;
  u16 *tcT0 = PS + 14 * MC,  *tcT1 = PS + 15 * MC;

  // ---- phase 0: prep z0 = attn2^T / (max colsum * max rowsum) ----
  {
    const float s = 1.f / __uint_as_float(*cmax);
    const float* basep = attn2 + ((long)bz << 16);
    float* mt = (float*)lds;  // [64][65] fp32 = 16.6KB
    const int r = t >> 2, cb = (t & 3) << 4;
#pragma unroll
    for (int c4 = 0; c4 < 16; c4 += 4) {
      float4 v = *(const float4*)&basep[(long)(n0 + r) * 256 + m0 + cb + c4];
      mt[r * 65 + cb + c4] = v.x; mt[r * 65 + cb + c4 + 1] = v.y;
      mt[r * 65 + cb + c4 + 2] = v.z; mt[r * 65 + cb + c4 + 3] = v.w;
    }
    __syncthreads();
    const int i = m0 + r;
#pragma unroll
    for (int c4 = 0; c4 < 16; c4 += 4) {
      float4 v = *(const float4*)&basep[(long)i * 256 + n0 + cb + c4];
      float vv[4] = {v.x, v.y, v.z, v.w};
#pragma unroll
      for (int e = 0; e < 4; ++e) {
        int j = n0 + cb + c4 + e;
        long idx = ((long)bz << 16) + ((long)i << 8) + j;
        float zt = vv[e] * s;  // zT layout (= attn2*s at [i][j])
        u16 zh = f2b(zt);
        zA_T0[idx] = zh; zA_T1[idx] = f2b(zt - b2f(zh));
        float zn = mt[(cb + c4 + e) * 65 + r] * s;  // zN (= attn2^T*s)
        u16 nh = f2b(zn);
        zA_N0[idx] = nh; zA_N1[idx] = f2b(zn - b2f(nh));
      }
    }
  }
  grid.sync();

  // ---- 6 Newton-Schulz iterations (0-2 plain bf16, 3-5 split) ----
  for (int it = 0; it < 6; ++it) {
    u16 *cN0, *cN1, *cT0, *cT1, *nN0, *nN1, *nT0, *nT1;
    if ((it & 1) == 0) {
      cN0 = zA_N0; cN1 = zA_N1; cT0 = zA_T0; cT1 = zA_T1;
      nN0 = zB_N0; nN1 = zB_N1; nT0 = zB_T0; nT1 = zB_T1;
    } else {
      cN0 = zB_N0; cN1 = zB_N1; cT0 = zB_T0; cT1 = zB_T1;
      nN0 = zA_N0; nN1 = zA_N1; nT0 = zA_T0; nT1 = zA_T1;
    }
    if (it < 3) {
      nn_tile<1>(aNhi, aNlo, cT0, cT1, azN0, azN1, azT0, azT1, 256, 1.f, 0.f, 0.f, bz, m0, n0, lds, t);
      grid.sync();
      nn_tile<1>(azN0, azN1, azT0, azT1, nullptr, nullptr, taT0, taT1, 256, 1.f, -7.f, 15.f, bz, m0, n0, lds, t);
      grid.sync();
      nn_tile<1>(azN0, azN1, taT0, taT1, nullptr, nullptr, tcT0, tcT1, 256, -1.f, 0.f, 13.f, bz, m0, n0, lds, t);
      grid.sync();
      nn_tile<1>(cN0, cN1, tcT0, tcT1, nN0, nN1, nT0, nT1, 256, 0.25f, 0.f, 0.f, bz, m0, n0, lds, t);
      grid.sync();
    } else {
      nn_tile<3>(aNhi, aNlo, cT0, cT1, azN0, azN1, azT0, azT1, 256, 1.f, 0.f, 0.f, bz, m0, n0, lds, t);
      grid.sync();
      nn_tile<3>(azN0, azN1, azT0, azT1, nullptr, nullptr, taT0, taT1, 256, 1.f, -7.f, 15.f, bz, m0, n0, lds, t);
      grid.sync();
      nn_tile<3>(azN0, azN1, taT0, taT1, nullptr, nullptr, tcT0, tcT1, 256, -1.f, 0.f, 13.f, bz, m0, n0, lds, t);
      grid.sync();
      nn_tile<3>(cN0, cN1, tcT0, tcT1, nN0, nN1, (it == 5) ? nullptr : nT0,
                 (it == 5) ? nullptr : nT1, 256, 0.25f, 0.f, 0.f, bz, m0, n0, lds, t);
      grid.sync();
    }
  }
  // ---- T2^T = (pinv @ T1)^T : final z is in zA set (6 swaps) ----
  if (tx == 0)
    nn_tile<3>(zA_N0, zA_N1, T1thi, T1tlo, nullptr, nullptr, T2t, nullptr, 64,
               1.f, 0.f, 0.f, bz, m0, 0, lds, t);
}

// ---------------- fused sim1: O = softmax(q @ k_land^T) @ T2 ----------------
__global__ __launch_bounds__(256) void k_fused_attn1(const u16* __restrict__ q,
                                                     const u16* __restrict__ klb,
                                                     const u16* __restrict__ t2t,
                                                     u16* __restrict__ O) {
  const int bh = blockIdx.y, n0 = blockIdx.x << 6;
  const int bb = bh >> 3, hh = bh & 7;
  const int t = threadIdx.x, lane = t & 63, w = t >> 6;
  const int fr = lane & 15, g = lane >> 4;
  __shared__ char lds[65536];
  {
    const u16* ks = klb + (long)bh * 16384;
    const u16* ts = t2t + (long)bh * 16384;
    int srow8 = lane >> 3, cs7 = lane & 7;
    int srow2 = lane >> 5, seg32 = lane & 31;
#pragma unroll
    for (int i = 0; i < 8; ++i) {
      int slab = w * 8 + i;
      int krow = slab * 8 + srow8;
      GLL(ks + krow * 64 + ((cs7 ^ (krow & 7)) << 3), lds + slab * 1024);
      int trow = slab * 2 + srow2;
      GLL(ts + trow * 256 + ((seg32 ^ (trow & 7)) << 3), lds + 32768 + slab * 1024);
    }
  }
  __syncthreads();
  const u16* qrow = q + ((long)bh * 8192 + n0 + (w << 4) + fr) * 64;
  bf16x8s qa0 = *(const bf16x8s*)(qrow + g * 8);
  bf16x8s qa1 = *(const bf16x8s*)(qrow + 32 + g * 8);
  f32x4 s[16];
#pragma unroll
  for (int c = 0; c < 16; ++c) {
    int j = (c << 4) + fr;
    bf16x8s b0 = *(const bf16x8s*)(lds + j * 128 + ((g ^ (j & 7)) << 4));
    bf16x8s b1 = *(const bf16x8s*)(lds + j * 128 + (((4 + g) ^ (j & 7)) << 4));
    f32x4 zz = {};
    zz = MFMA(qa0, b0, zz, 0, 0, 0);
    zz = MFMA(qa1, b1, zz, 0, 0, 0);
    s[c] = zz;
  }
  float li[4];
#pragma unroll
  for (int r = 0; r < 4; ++r) {
    float m = s[0][r];
#pragma unroll
    for (int c = 1; c < 16; ++c) m = fmaxf(m, s[c][r]);
    m = fmaxf(m, __shfl_xor(m, 1, 64));
    m = fmaxf(m, __shfl_xor(m, 2, 64));
    m = fmaxf(m, __shfl_xor(m, 4, 64));
    m = fmaxf(m, __shfl_xor(m, 8, 64));
    float l = 0.f;
#pragma unroll
    for (int c = 0; c < 16; ++c) {
      float e = __expf(s[c][r] - m);
      s[c][r] = e;
      l += e;
    }
    l += __shfl_xor(l, 1, 64);
    l += __shfl_xor(l, 2, 64);
    l += __shfl_xor(l, 4, 64);
    l += __shfl_xor(l, 8, 64);
    li[r] = 1.f / l;
  }
  __syncthreads();
#pragma unroll
  for (int c = 0; c < 16; ++c)
#pragma unroll
    for (int r = 0; r < 4; ++r) {
      int row = (w << 4) + (g << 2) + r;
      int byin = (c << 5) + (fr << 1);
      *(u16*)(lds + row * 512 + (byin ^ ((row & 7) << 4))) = f2b(s[c][r]);
    }
  asm volatile("s_waitcnt lgkmcnt(0)" ::: "memory");
  __builtin_amdgcn_sched_barrier(0);
  f32x4 o4[4] = {};
#pragma unroll
  for (int ss = 0; ss < 8; ++ss) {
    int prow = (w << 4) + fr;
    bf16x8s ap = *(const bf16x8s*)(lds + prow * 512 +
                                   (((ss * 64) + (g << 4)) ^ ((prow & 7) << 4)));
#pragma unroll
    for (int d = 0; d < 4; ++d) {
      int dh = (d << 4) + fr;
      bf16x8s bv = *(const bf16x8s*)(lds + 32768 + dh * 512 +
                                     (((ss * 4 + g) ^ (dh & 7)) << 4));
      o4[d] = MFMA(ap, bv, o4[d], 0, 0, 0);
    }
  }
  u16* ob = O + (((long)bb * 8192 + n0 + (w << 4)) << 9) + (hh << 6);
#pragma unroll
  for (int d = 0; d < 4; ++d)
#pragma unroll
    for (int r = 0; r < 4; ++r) {
      int row = (g << 2) + r;
      int col = (d << 4) + fr;
      ob[((long)row << 9) + col] = f2b(o4[d][r] * li[r]);
    }
}

// ---------------- host ----------------
extern "C" void kernel_launch(void* const* d_in, const int* in_sizes, int n_in,
                              void* d_out, int out_size, void* d_ws, size_t ws_size,
                              hipStream_t stream) {
  const float* x = (const float*)d_in[0];
  const float* z = (const float*)d_in[1];
  const float* Wq = (const float*)d_in[2];
  const float* Wkv = (const float*)d_in[3];
  const float* Wo = (const float*)d_in[4];
  const float* bo = (const float*)d_in[5];
  float* out = (float*)d_out;

  char* base = (char*)d_ws;
  size_t off = 0;
  auto alloc = [&](size_t bytes) -> void* {
    void* r = base + off;
    off = (off + bytes + 255) & ~(size_t)255;
    return r;
  };
  u16* qb = (u16*)alloc(33554432);
  u16* kb = (u16*)alloc(16777216);
  u16* vtb = (u16*)alloc(16777216);
  u16* PS = (u16*)alloc(67108864);    // T1 partials, then pinv state (16 x 4MB)
  float* attn2 = (float*)alloc(8388608);
  u16* xb = (u16*)alloc(33554432);    // dead after qproj -> Ob
  u16* zb = (u16*)alloc(16777216);    // dead after kvproj -> attn2 split aN
  u16* wqt = (u16*)alloc(524288);
  u16* wkvt = (u16*)alloc(1048576);
  u16* wot = (u16*)alloc(524288);
  u16* qlh = (u16*)alloc(1048576);
  u16* qll = (u16*)alloc(1048576);
  u16* klh = (u16*)alloc(1048576);
  u16* kll = (u16*)alloc(1048576);
  u16* T1t = (u16*)alloc(2097152);
  u16* T2t = (u16*)alloc(1048576);    // T2^T [bh][64 dh][256 m]
  unsigned* cmax = (unsigned*)alloc(256);
  const long MC = 2097152;
  u16 *aNhi = zb, *aNlo = zb + MC;
  float* opart = (float*)PS;                 // 8.4MB partials (consumed before coop)
  float* pm_ = opart + 2097152;
  float* pl_ = pm_ + 32768;
  u16* T1thi = T1t;
  u16* T1tlo = T1t + 524288;
  u16* Ob = xb;

  hipMemsetAsync(cmax, 0, 4, stream);
  k_f2b<<<16384, 256, 0, stream>>>(x, xb, 4194304);
  k_f2b<<<8192, 256, 0, stream>>>(z, zb, 2097152);
  k_wt<<<1024, 256, 0, stream>>>(Wq, wqt, 512);
  k_wt<<<2048, 256, 0, stream>>>(Wkv, wkvt, 1024);
  k_wt<<<1024, 256, 0, stream>>>(Wo, wot, 512);

  k_gemm128<0><<<dim3(4, 256), 256, 0, stream>>>(xb, wqt, qb, nullptr, nullptr,
                                                 nullptr, 512);
  k_gemm128<1><<<dim3(8, 128), 256, 0, stream>>>(zb, wkvt, kb, vtb, nullptr,
                                                 nullptr, 512);
  k_landmark<<<2048, 256, 0, stream>>>(qb, qlh, qll, 8192, 32, 1.f / 32.f);
  k_landmark<<<2048, 256, 0, stream>>>(kb, klh, kll, 4096, 16, 1.f / 16.f);

  k_sim2<<<dim3(4, 32), 256, 0, stream>>>(qlh, qll, klh, kll, attn2, aNhi, aNlo);
  k_colmax<<<32, 256, 0, stream>>>(attn2, cmax);

  k_t1part<<<512, 256, 0, stream>>>(qlh, kb, vtb, opart, pm_, pl_);
  k_t1merge<<<dim3(4, 32), 256, 0, stream>>>(opart, pm_, pl_, T1thi, T1tlo);

  // cooperative fused pinv: prep + 6 NS iterations + T2^T (single launch)
  {
    const u16* a0 = aNhi; const u16* a1 = aNlo;
    u16* ps = PS; const float* at2 = attn2; const unsigned* cm = cmax;
    const u16* t1h = T1thi; const u16* t1l = T1tlo; u16* t2 = T2t;
    void* cargs[8] = {&a0, &a1, &ps, &at2, &cm, &t1h, &t1l, &t2};
    hipLaunchCooperativeKernel((void*)k_pinv_coop, dim3(512), dim3(256), cargs,
                               0, stream);
  }

  k_fused_attn1<<<dim3(128, 32), 256, 0, stream>>>(qb, klh, T2t, Ob);
  k_gemm128<2><<<dim3(4, 256), 256, 0, stream>>>(Ob, wot, out, nullptr, x, bo, 512);
}

// Round 9
// 634.898 us; speedup vs baseline: 4.0619x; 4.0619x over previous
//
#include <hip/hip_runtime.h>

typedef unsigned short u16;
typedef __attribute__((ext_vector_type(8))) short bf16x8s;
typedef __attribute__((ext_vector_type(4))) float f32x4;

#define DEV static __device__ __forceinline__

DEV float b2f(u16 v) { return __uint_as_float(((unsigned)v) << 16); }
DEV u16 f2b(float f) {
  unsigned u = __float_as_uint(f);
  unsigned r = (u + 0x7fffu + ((u >> 16) & 1u)) >> 16;
  return (u16)r;
}

// async global->LDS, 16B per lane; lds base must be wave-uniform (HW adds lane*16)
#define GLL(gp, lp)                                                            \
  __builtin_amdgcn_global_load_lds(                                            \
      (const __attribute__((address_space(1))) unsigned int*)(gp),             \
      (__attribute__((address_space(3))) unsigned int*)(lp), 16, 0, 0)

#define MFMA __builtin_amdgcn_mfma_f32_16x16x32_bf16

// ---------------- elementwise converts ----------------
__global__ __launch_bounds__(256) void k_f2b(const float* __restrict__ in,
                                             u16* __restrict__ o, long n4) {
  long i = (long)blockIdx.x * 256 + threadIdx.x;
  if (i >= n4) return;
  float4 v = *(const float4*)(in + i * 4);
  u16* d = o + i * 4;
  d[0] = f2b(v.x); d[1] = f2b(v.y); d[2] = f2b(v.z); d[3] = f2b(v.w);
}

// W[k][N] (fp32) -> Wt[n][512] bf16  (K fixed = 512)
__global__ __launch_bounds__(256) void k_wt(const float* __restrict__ W,
                                            u16* __restrict__ Wt, int N) {
  int e = blockIdx.x * 256 + threadIdx.x;  // e < N*512
  int nn = e >> 9, kk = e & 511;
  Wt[e] = f2b(W[(long)kk * N + nn]);
}

// ---------------- 128x128 bf16 NT GEMM (BK=64, global_load_lds, swizzled) ----
template <int MODE>
__global__ __launch_bounds__(256, 2) void k_gemm128(
    const u16* __restrict__ A, const u16* __restrict__ Bm, void* __restrict__ C0,
    void* __restrict__ C1, const float* __restrict__ xres,
    const float* __restrict__ bias, int K) {
  const int nwg = gridDim.x * gridDim.y;
  const int orig = blockIdx.y * gridDim.x + blockIdx.x;
  const int qq = nwg >> 3, rr = nwg & 7;
  const int xcd = orig & 7, loc = orig >> 3;
  const int swz = (xcd < rr ? xcd * (qq + 1) : rr * (qq + 1) + (xcd - rr) * qq) + loc;
  const int m0 = (swz / gridDim.x) << 7, n0 = (swz % gridDim.x) << 7;
  const int t = threadIdx.x, lane = t & 63, w = t >> 6;
  const int wm = (w >> 1) << 6, wn = (w & 1) << 6;
  const int fr = lane & 15, g = lane >> 4;
  __shared__ u16 As[8192];
  __shared__ u16 Bs[8192];
  f32x4 acc[4][4] = {};
  const int srow = t >> 3, scs = t & 7;
  for (int k0 = 0; k0 < K; k0 += 64) {
    __syncthreads();
#pragma unroll
    for (int i = 0; i < 4; ++i) {
      int row = srow + (i << 5), cs = scs;
      GLL(A + (long)(m0 + row) * K + k0 + ((cs ^ (row & 7)) << 3),
          &As[(i << 11) + (w << 9)]);
      GLL(Bm + (long)(n0 + row) * K + k0 + ((cs ^ (row & 7)) << 3),
          &Bs[(i << 11) + (w << 9)]);
    }
    __syncthreads();
#pragma unroll
    for (int ks = 0; ks < 2; ++ks) {
      bf16x8s af[4], bf[4];
#pragma unroll
      for (int fi = 0; fi < 4; ++fi) {
        int row = wm + fi * 16 + fr;
        af[fi] = *(const bf16x8s*)((const char*)As + row * 128 +
                                   (((ks * 4 + g) ^ (row & 7)) << 4));
      }
#pragma unroll
      for (int fj = 0; fj < 4; ++fj) {
        int row = wn + fj * 16 + fr;
        bf[fj] = *(const bf16x8s*)((const char*)Bs + row * 128 +
                                   (((ks * 4 + g) ^ (row & 7)) << 4));
      }
#pragma unroll
      for (int fi = 0; fi < 4; ++fi)
#pragma unroll
        for (int fj = 0; fj < 4; ++fj)
          acc[fi][fj] = MFMA(af[fi], bf[fj], acc[fi][fj], 0, 0, 0);
    }
  }
  const int crow = g << 2;
#pragma unroll
  for (int fi = 0; fi < 4; ++fi)
#pragma unroll
    for (int fj = 0; fj < 4; ++fj)
#pragma unroll
      for (int r = 0; r < 4; ++r) {
        int row = m0 + wm + fi * 16 + crow + r;
        int col = n0 + wn + fj * 16 + fr;
        float v = acc[fi][fj][r];
        if (MODE == 0) {
          int b = row >> 13, n = row & 8191, h = col >> 6, dh = col & 63;
          ((u16*)C0)[((((long)(b * 8 + h)) << 13) + n) * 64 + dh] = f2b(v * 0.125f);
        } else if (MODE == 1) {
          int b = row >> 12, nz = row & 4095;
          if (col < 512) {
            int h = col >> 6, dh = col & 63;
            ((u16*)C0)[((((long)(b * 8 + h)) << 12) + nz) * 64 + dh] = f2b(v);
          } else {
            int c2 = col - 512, h = c2 >> 6, dh = c2 & 63;
            ((u16*)C1)[((((long)(b * 8 + h) * 64 + dh)) << 12) + nz] = f2b(v);
          }
        } else if (MODE == 2) {
          long idx = ((long)row << 9) + col;
          ((float*)C0)[idx] = v + xres[idx] + bias[col];
        }
      }
}

// ---------------- landmarks: mean over groups -> split hi/lo bf16 -----------
__global__ __launch_bounds__(256) void k_landmark(const u16* __restrict__ src,
                                                  u16* __restrict__ hi,
                                                  u16* __restrict__ lo, int ntok,
                                                  int l, float inv) {
  int pidx = blockIdx.x * 4 + (threadIdx.x >> 6);
  int d = threadIdx.x & 63;
  int bh = pidx >> 8, m = pidx & 255;
  const u16* s = src + ((long)bh * ntok + (long)m * l) * 64 + d;
  float sum = 0.f;
  for (int j = 0; j < l; ++j) sum += b2f(s[j * 64]);
  sum *= inv;
  long o = ((long)bh * 256 + m) * 64 + d;
  u16 h = f2b(sum);
  hi[o] = h;
  lo[o] = f2b(sum - b2f(h));
}

// ---------------- sim2 + softmax via split-bf16 MFMA ------------------------
__global__ __launch_bounds__(256, 2) void k_sim2(
    const u16* __restrict__ qlh, const u16* __restrict__ qll,
    const u16* __restrict__ klh, const u16* __restrict__ kll,
    float* __restrict__ attn2, u16* __restrict__ aNhi, u16* __restrict__ aNlo) {
  const int rb = blockIdx.x, bh = blockIdx.y;
  const int t = threadIdx.x, lane = t & 63, w = t >> 6;
  const int fr = lane & 15, g = lane >> 4;
  __shared__ char lds[65536];  // [0,32K) k_land hi ; [32K,64K) k_land lo
  {
    const u16* kh = klh + (long)bh * 16384;
    const u16* kl = kll + (long)bh * 16384;
    int srow8 = lane >> 3, cs7 = lane & 7;
#pragma unroll
    for (int i = 0; i < 8; ++i) {
      int slab = w * 8 + i;
      int krow = slab * 8 + srow8;
      GLL(kh + krow * 64 + ((cs7 ^ (krow & 7)) << 3), lds + slab * 1024);
      GLL(kl + krow * 64 + ((cs7 ^ (krow & 7)) << 3), lds + 32768 + slab * 1024);
    }
  }
  long qoff = ((long)bh * 256 + rb * 64 + w * 16 + fr) * 64;
  bf16x8s qh0 = *(const bf16x8s*)(qlh + qoff + g * 8);
  bf16x8s qh1 = *(const bf16x8s*)(qlh + qoff + 32 + g * 8);
  bf16x8s ql0 = *(const bf16x8s*)(qll + qoff + g * 8);
  bf16x8s ql1 = *(const bf16x8s*)(qll + qoff + 32 + g * 8);
  __syncthreads();
  f32x4 s[16];
#pragma unroll
  for (int c = 0; c < 16; ++c) {
    int j = (c << 4) + fr;
    int o0 = j * 128 + ((g ^ (j & 7)) << 4);
    int o1 = j * 128 + (((4 + g) ^ (j & 7)) << 4);
    bf16x8s kh0 = *(const bf16x8s*)(lds + o0);
    bf16x8s kh1 = *(const bf16x8s*)(lds + o1);
    bf16x8s kl0 = *(const bf16x8s*)(lds + 32768 + o0);
    bf16x8s kl1 = *(const bf16x8s*)(lds + 32768 + o1);
    f32x4 zz = {};
    zz = MFMA(qh0, kh0, zz, 0, 0, 0);
    zz = MFMA(qh1, kh1, zz, 0, 0, 0);
    zz = MFMA(qh0, kl0, zz, 0, 0, 0);
    zz = MFMA(qh1, kl1, zz, 0, 0, 0);
    zz = MFMA(ql0, kh0, zz, 0, 0, 0);
    zz = MFMA(ql1, kh1, zz, 0, 0, 0);
    s[c] = zz;
  }
  float li[4];
#pragma unroll
  for (int r = 0; r < 4; ++r) {
    float m = s[0][r];
#pragma unroll
    for (int c = 1; c < 16; ++c) m = fmaxf(m, s[c][r]);
    m = fmaxf(m, __shfl_xor(m, 1, 64));
    m = fmaxf(m, __shfl_xor(m, 2, 64));
    m = fmaxf(m, __shfl_xor(m, 4, 64));
    m = fmaxf(m, __shfl_xor(m, 8, 64));
    float l = 0.f;
#pragma unroll
    for (int c = 0; c < 16; ++c) {
      float e = __expf(s[c][r] - m);
      s[c][r] = e;
      l += e;
    }
    l += __shfl_xor(l, 1, 64);
    l += __shfl_xor(l, 2, 64);
    l += __shfl_xor(l, 4, 64);
    l += __shfl_xor(l, 8, 64);
    li[r] = 1.f / l;
  }
#pragma unroll
  for (int c = 0; c < 16; ++c)
#pragma unroll
    for (int r = 0; r < 4; ++r) {
      int row = rb * 64 + w * 16 + (g << 2) + r;
      int col = (c << 4) + fr;
      long idx = ((long)bh << 16) + ((long)row << 8) + col;
      float p = s[c][r] * li[r];
      attn2[idx] = p;
      u16 h = f2b(p);
      aNhi[idx] = h;
      aNlo[idx] = f2b(p - b2f(h));
    }
}

__global__ __launch_bounds__(256) void k_colmax(const float* __restrict__ attn2,
                                                unsigned* __restrict__ cmax) {
  int bh = blockIdx.x, j = threadIdx.x, lane = j & 63, w = j >> 6;
  const float* p = attn2 + ((long)bh << 16) + j;
  float s = 0.f;
  for (int m = 0; m < 256; ++m) s += p[m * 256];
  float mx = s;
  for (int o = 1; o < 64; o <<= 1) mx = fmaxf(mx, __shfl_xor(mx, o, 64));
  __shared__ float r1[4];
  if (lane == 0) r1[w] = mx;
  __syncthreads();
  if (j == 0) {
    mx = fmaxf(fmaxf(r1[0], r1[1]), fmaxf(r1[2], r1[3]));
    atomicMax(cmax, __float_as_uint(mx));
  }
}

// ---------------- T1 split-KV partial: (bh, rb, kc of 1024 keys) ------------
__global__ __launch_bounds__(256, 2) void k_t1part(
    const u16* __restrict__ qlb, const u16* __restrict__ kb,
    const u16* __restrict__ vtb, float* __restrict__ opart,
    float* __restrict__ pm_, float* __restrict__ pl_) {
  int orig = blockIdx.x;  // 512 = 32 bh * 4 kc * 4 rb
  int xcd = orig & 7, idx = orig >> 3;
  int p = xcd * 16 + (idx >> 2);  // (bh,kc) pair; 4 rb of a pair share an XCD
  int rb = idx & 3;
  int bh = p >> 2, kc = p & 3;
  const int t = threadIdx.x, lane = t & 63, w = t >> 6;
  const int fr = lane & 15, g = lane >> 4;
  __shared__ char lds[65536];  // [0,32K) K chunk (aliased by P); [32K,64K) V^T
  const u16* qrow = qlb + ((long)bh * 256 + rb * 64 + w * 16 + fr) * 64;
  bf16x8s qa0 = *(const bf16x8s*)(qrow + g * 8);
  bf16x8s qa1 = *(const bf16x8s*)(qrow + 32 + g * 8);
  f32x4 o[4] = {};
  float m[4] = {-3e38f, -3e38f, -3e38f, -3e38f};
  float l[4] = {};
  const long kbase = (long)bh * 262144;
  for (int cc = 0; cc < 4; ++cc) {
    int c0 = kc * 1024 + cc * 256;
    __syncthreads();
#pragma unroll
    for (int i = 0; i < 8; ++i) {
      int seg = (i << 8) + t, row = seg >> 3, cs = seg & 7;
      GLL(kb + kbase + (long)(c0 + row) * 64 + ((cs ^ (row & 7)) << 3),
          lds + (i << 12) + (w << 10));
    }
#pragma unroll
    for (int i = 0; i < 8; ++i) {
      int seg = (i << 8) + t, row = seg >> 5, cs = seg & 31;
      GLL(vtb + kbase + (long)row * 4096 + c0 + ((cs ^ (row & 7)) << 3),
          lds + 32768 + (i << 12) + (w << 10));
    }
    __syncthreads();
    f32x4 s[16];
#pragma unroll
    for (int c = 0; c < 16; ++c) {
      int j = c * 16 + fr;
      bf16x8s b0 = *(const bf16x8s*)(lds + j * 128 + ((g ^ (j & 7)) << 4));
      bf16x8s b1 = *(const bf16x8s*)(lds + j * 128 + (((4 + g) ^ (j & 7)) << 4));
      f32x4 zz = {};
      zz = MFMA(qa0, b0, zz, 0, 0, 0);
      zz = MFMA(qa1, b1, zz, 0, 0, 0);
      s[c] = zz;
    }
    float sc[4];
#pragma unroll
    for (int r = 0; r < 4; ++r) {
      float pm = s[0][r];
#pragma unroll
      for (int c = 1; c < 16; ++c) pm = fmaxf(pm, s[c][r]);
      pm = fmaxf(pm, __shfl_xor(pm, 1, 64));
      pm = fmaxf(pm, __shfl_xor(pm, 2, 64));
      pm = fmaxf(pm, __shfl_xor(pm, 4, 64));
      pm = fmaxf(pm, __shfl_xor(pm, 8, 64));
      float mn = fmaxf(m[r], pm);
      sc[r] = __expf(m[r] - mn);
      m[r] = mn;
    }
#pragma unroll
    for (int r = 0; r < 4; ++r) {
      float su = 0.f;
#pragma unroll
      for (int c = 0; c < 16; ++c) {
        float e = __expf(s[c][r] - m[r]);
        s[c][r] = e;
        su += e;
      }
      su += __shfl_xor(su, 1, 64);
      su += __shfl_xor(su, 2, 64);
      su += __shfl_xor(su, 4, 64);
      su += __shfl_xor(su, 8, 64);
      l[r] = l[r] * sc[r] + su;
    }
#pragma unroll
    for (int d = 0; d < 4; ++d)
#pragma unroll
      for (int r = 0; r < 4; ++r) o[d][r] *= sc[r];
    __syncthreads();
#pragma unroll
    for (int c = 0; c < 16; ++c)
#pragma unroll
      for (int r = 0; r < 4; ++r) {
        int row = (w << 4) + (g << 2) + r;
        int byin = (c << 5) + (fr << 1);
        *(u16*)(lds + row * 512 + (byin ^ ((row & 7) << 4))) = f2b(s[c][r]);
      }
    asm volatile("s_waitcnt lgkmcnt(0)" ::: "memory");
    __builtin_amdgcn_sched_barrier(0);
#pragma unroll
    for (int ss = 0; ss < 8; ++ss) {
      int prow = (w << 4) + fr;
      bf16x8s ap = *(const bf16x8s*)(lds + prow * 512 +
                                     (((ss * 64) + (g << 4)) ^ ((prow & 7) << 4)));
#pragma unroll
      for (int d = 0; d < 4; ++d) {
        int dh = (d << 4) + fr;
        bf16x8s bv = *(const bf16x8s*)(lds + 32768 + dh * 512 +
                                       (((ss * 4 + g) ^ (dh & 7)) << 4));
        o[d] = MFMA(ap, bv, o[d], 0, 0, 0);
      }
    }
  }
  // LDS-transpose o then coalesced float4 writes
  __syncthreads();
  float* lf = (float*)lds;
#pragma unroll
  for (int d = 0; d < 4; ++d)
#pragma unroll
    for (int r = 0; r < 4; ++r)
      lf[((w << 4) + (g << 2) + r) * 76 + (d << 4) + fr] = o[d][r];
  __syncthreads();
  const long pb = (long)(bh * 4 + kc) * 256 + rb * 64;
#pragma unroll
  for (int i = 0; i < 4; ++i) {
    int row = i * 16 + (t >> 4);
    int c4 = (t & 15) << 2;
    float4 v = *(const float4*)&lf[row * 76 + c4];
    *(float4*)&opart[(pb + row) * 64 + c4] = v;
  }
  if (fr == 0) {
#pragma unroll
    for (int r = 0; r < 4; ++r) {
      int lr = (w << 4) + (g << 2) + r;
      pm_[pb + lr] = m[r];
      pl_[pb + lr] = l[r];
    }
  }
}

// ---------------- merge 4 partials -> T1^T split bf16 -----------------------
__global__ __launch_bounds__(256) void k_t1merge(
    const float* __restrict__ opart, const float* __restrict__ pm_,
    const float* __restrict__ pl_, u16* __restrict__ T1thi,
    u16* __restrict__ T1tlo) {
  const int rb = blockIdx.x, bh = blockIdx.y;
  const int t = threadIdx.x;
#pragma unroll
  for (int rp = 0; rp < 4; ++rp) {
    int row = rb * 64 + rp * 16 + (t >> 4);
    int dh4 = (t & 15) << 2;
    float pmv[4], M = -3e38f;
#pragma unroll
    for (int i = 0; i < 4; ++i) {
      pmv[i] = pm_[(long)(bh * 4 + i) * 256 + row];
      M = fmaxf(M, pmv[i]);
    }
    float L = 0.f, wt[4];
#pragma unroll
    for (int i = 0; i < 4; ++i) {
      wt[i] = __expf(pmv[i] - M);
      L += pl_[(long)(bh * 4 + i) * 256 + row] * wt[i];
    }
    float4 acc = {0.f, 0.f, 0.f, 0.f};
#pragma unroll
    for (int i = 0; i < 4; ++i) {
      float4 v = *(const float4*)&opart[((long)(bh * 4 + i) * 256 + row) * 64 + dh4];
      acc.x += v.x * wt[i]; acc.y += v.y * wt[i];
      acc.z += v.z * wt[i]; acc.w += v.w * wt[i];
    }
    float invL = 1.f / L;
    float vv[4] = {acc.x * invL, acc.y * invL, acc.z * invL, acc.w * invL};
#pragma unroll
    for (int e = 0; e < 4; ++e) {
      int dh = dh4 + e;
      long idx = (long)bh * 16384 + (long)dh * 256 + row;
      u16 h = f2b(vv[e]);
      T1thi[idx] = h;
      T1tlo[idx] = f2b(vv[e] - b2f(h));
    }
  }
}

// ---------------- MFMA NN GEMM (pinv chain); NP=1 plain bf16, NP=3 split ----
template <int NP>
__global__ __launch_bounds__(256) void k_nn_mfma(
    const u16* __restrict__ Ahi, const u16* __restrict__ Alo,
    const u16* __restrict__ Bthi, const u16* __restrict__ Btlo,
    u16* __restrict__ CNhi, u16* __restrict__ CNlo,
    u16* __restrict__ CThi, u16* __restrict__ CTlo,
    int Nc, float sab, float sa, float cdiag) {
  const int bz = blockIdx.z;
  const long offA = (long)bz << 16;
  const long offB = (long)bz * ((long)Nc << 8);
  const int m0 = blockIdx.y << 6, n0 = blockIdx.x << 6;
  const int t = threadIdx.x, lane = t & 63, w = t >> 6;
  const int wm = (w >> 1) << 5, wn = (w & 1) << 5;
  const int fr = lane & 15, g = lane >> 4;
  __shared__ u16 lds[16384];
  u16* LAh = lds;
  u16* LAl = lds + 4096;
  u16* LBh = lds + 8192;
  u16* LBl = lds + 12288;
  f32x4 acc[2][2] = {};
  const int srow8 = lane >> 3, cs = lane & 7;
  for (int k0 = 0; k0 < 256; k0 += 64) {
    __syncthreads();
#pragma unroll
    for (int j = 0; j < 2; ++j) {
      int slab = w * 2 + j;
      int row = slab * 8 + srow8;
      long asrc = offA + (long)(m0 + row) * 256 + k0 + ((cs ^ (row & 7)) << 3);
      long bsrc = offB + (long)(n0 + row) * 256 + k0 + ((cs ^ (row & 7)) << 3);
      GLL(Ahi + asrc, LAh + slab * 512);
      GLL(Bthi + bsrc, LBh + slab * 512);
      if (NP == 3) {
        GLL(Alo + asrc, LAl + slab * 512);
        GLL(Btlo + bsrc, LBl + slab * 512);
      }
    }
    __syncthreads();
#pragma unroll
    for (int ks = 0; ks < 2; ++ks) {
      const int ra0 = wm + fr, ra1 = wm + 16 + fr;
      const int rb0 = wn + fr, rb1 = wn + 16 + fr;
#define RD(base, row) \
  (*(const bf16x8s*)((const char*)(base) + (row) * 128 + (((ks * 4 + g) ^ ((row) & 7)) << 4)))
      bf16x8s ah0 = RD(LAh, ra0), ah1 = RD(LAh, ra1);
      bf16x8s bh0 = RD(LBh, rb0), bh1 = RD(LBh, rb1);
      acc[0][0] = MFMA(ah0, bh0, acc[0][0], 0, 0, 0);
      acc[0][1] = MFMA(ah0, bh1, acc[0][1], 0, 0, 0);
      acc[1][0] = MFMA(ah1, bh0, acc[1][0], 0, 0, 0);
      acc[1][1] = MFMA(ah1, bh1, acc[1][1], 0, 0, 0);
      if (NP == 3) {
        bf16x8s al0 = RD(LAl, ra0), al1 = RD(LAl, ra1);
        bf16x8s bl0 = RD(LBl, rb0), bl1 = RD(LBl, rb1);
        acc[0][0] = MFMA(ah0, bl0, acc[0][0], 0, 0, 0);
        acc[0][0] = MFMA(al0, bh0, acc[0][0], 0, 0, 0);
        acc[0][1] = MFMA(ah0, bl1, acc[0][1], 0, 0, 0);
        acc[0][1] = MFMA(al0, bh1, acc[0][1], 0, 0, 0);
        acc[1][0] = MFMA(ah1, bl0, acc[1][0], 0, 0, 0);
        acc[1][0] = MFMA(al1, bh0, acc[1][0], 0, 0, 0);
        acc[1][1] = MFMA(ah1, bl1, acc[1][1], 0, 0, 0);
        acc[1][1] = MFMA(al1, bh1, acc[1][1], 0, 0, 0);
      }
#undef RD
    }
  }
  const int crow = g << 2;
  const long offC = (long)bz * ((long)Nc << 8);
#pragma unroll
  for (int i = 0; i < 2; ++i)
#pragma unroll
    for (int j = 0; j < 2; ++j)
#pragma unroll
      for (int r = 0; r < 4; ++r) {
        int row = m0 + wm + i * 16 + crow + r;
        int col = n0 + wn + j * 16 + fr;
        float v = sab * acc[i][j][r];
        if (sa != 0.f) {
          long ai = offA + ((long)row << 8) + col;
          v += sa * (b2f(Ahi[ai]) + b2f(Alo[ai]));
        }
        if (row == col) v += cdiag;
        if (CNhi) {
          long ci = offC + (long)row * Nc + col;
          u16 h = f2b(v);
          if (CNlo) { CNhi[ci] = h; CNlo[ci] = f2b(v - b2f(h)); }
          else CNhi[ci] = h;
        }
        if (CThi) {
          long ti = offC + ((long)col << 8) + row;
          u16 h = f2b(v);
          CThi[ti] = h;
          if (CTlo) CTlo[ti] = f2b(v - b2f(h));
        }
      }
}

// ---------------- pinv operand prep (z0 only; aN written by k_sim2) ---------
__global__ __launch_bounds__(256) void k_prep_pinv(
    const float* __restrict__ attn2, const unsigned* __restrict__ cmax,
    u16* __restrict__ zNhi, u16* __restrict__ zNlo,
    u16* __restrict__ zThi, u16* __restrict__ zTlo) {
  const int bz = blockIdx.z, i0 = blockIdx.y << 6, j0 = blockIdx.x << 6;
  const float s = 1.f / __uint_as_float(*cmax);
  const float* base = attn2 + ((long)bz << 16);
  __shared__ float mt[64][65];
  const int r = threadIdx.x >> 2, cb = (threadIdx.x & 3) << 4;
#pragma unroll
  for (int c4 = 0; c4 < 16; c4 += 4) {
    float4 v = *(const float4*)&base[(long)(j0 + r) * 256 + i0 + cb + c4];
    mt[r][cb + c4] = v.x; mt[r][cb + c4 + 1] = v.y;
    mt[r][cb + c4 + 2] = v.z; mt[r][cb + c4 + 3] = v.w;
  }
  __syncthreads();
  const int i = i0 + r;
#pragma unroll
  for (int c4 = 0; c4 < 16; c4 += 4) {
    float4 v = *(const float4*)&base[(long)i * 256 + j0 + cb + c4];
    float vv[4] = {v.x, v.y, v.z, v.w};
#pragma unroll
    for (int e = 0; e < 4; ++e) {
      int j = j0 + cb + c4 + e;
      long idx = ((long)bz << 16) + ((long)i << 8) + j;
      float zt = vv[e] * s;
      u16 zh = f2b(zt);
      zThi[idx] = zh; zTlo[idx] = f2b(zt - b2f(zh));
      float zn = mt[cb + c4 + e][r] * s;
      u16 nh = f2b(zn);
      zNhi[idx] = nh; zNlo[idx] = f2b(zn - b2f(nh));
    }
  }
}

// ---------------- fused sim1: O = softmax(q @ k_land^T) @ T2 ----------------
__global__ __launch_bounds__(256) void k_fused_attn1(const u16* __restrict__ q,
                                                     const u16* __restrict__ klb,
                                                     const u16* __restrict__ t2t,
                                                     u16* __restrict__ O) {
  const int bh = blockIdx.y, n0 = blockIdx.x << 6;
  const int bb = bh >> 3, hh = bh & 7;
  const int t = threadIdx.x, lane = t & 63, w = t >> 6;
  const int fr = lane & 15, g = lane >> 4;
  __shared__ char lds[65536];
  {
    const u16* ks = klb + (long)bh * 16384;
    const u16* ts = t2t + (long)bh * 16384;
    int srow8 = lane >> 3, cs7 = lane & 7;
    int srow2 = lane >> 5, seg32 = lane & 31;
#pragma unroll
    for (int i = 0; i < 8; ++i) {
      int slab = w * 8 + i;
      int krow = slab * 8 + srow8;
      GLL(ks + krow * 64 + ((cs7 ^ (krow & 7)) << 3), lds + slab * 1024);
      int trow = slab * 2 + srow2;
      GLL(ts + trow * 256 + ((seg32 ^ (trow & 7)) << 3), lds + 32768 + slab * 1024);
    }
  }
  __syncthreads();
  const u16* qrow = q + ((long)bh * 8192 + n0 + (w << 4) + fr) * 64;
  bf16x8s qa0 = *(const bf16x8s*)(qrow + g * 8);
  bf16x8s qa1 = *(const bf16x8s*)(qrow + 32 + g * 8);
  f32x4 s[16];
#pragma unroll
  for (int c = 0; c < 16; ++c) {
    int j = (c << 4) + fr;
    bf16x8s b0 = *(const bf16x8s*)(lds + j * 128 + ((g ^ (j & 7)) << 4));
    bf16x8s b1 = *(const bf16x8s*)(lds + j * 128 + (((4 + g) ^ (j & 7)) << 4));
    f32x4 zz = {};
    zz = MFMA(qa0, b0, zz, 0, 0, 0);
    zz = MFMA(qa1, b1, zz, 0, 0, 0);
    s[c] = zz;
  }
  float li[4];
#pragma unroll
  for (int r = 0; r < 4; ++r) {
    float m = s[0][r];
#pragma unroll
    for (int c = 1; c < 16; ++c) m = fmaxf(m, s[c][r]);
    m = fmaxf(m, __shfl_xor(m, 1, 64));
    m = fmaxf(m, __shfl_xor(m, 2, 64));
    m = fmaxf(m, __shfl_xor(m, 4, 64));
    m = fmaxf(m, __shfl_xor(m, 8, 64));
    float l = 0.f;
#pragma unroll
    for (int c = 0; c < 16; ++c) {
      float e = __expf(s[c][r] - m);
      s[c][r] = e;
      l += e;
    }
    l += __shfl_xor(l, 1, 64);
    l += __shfl_xor(l, 2, 64);
    l += __shfl_xor(l, 4, 64);
    l += __shfl_xor(l, 8, 64);
    li[r] = 1.f / l;
  }
  __syncthreads();  // all waves done reading k_land; reuse region as P[64][256]
#pragma unroll
  for (int c = 0; c < 16; ++c)
#pragma unroll
    for (int r = 0; r < 4; ++r) {
      int row = (w << 4) + (g << 2) + r;
      int byin = (c << 5) + (fr << 1);
      *(u16*)(lds + row * 512 + (byin ^ ((row & 7) << 4))) = f2b(s[c][r]);
    }
  asm volatile("s_waitcnt lgkmcnt(0)" ::: "memory");
  __builtin_amdgcn_sched_barrier(0);
  f32x4 o4[4] = {};
#pragma unroll
  for (int ss = 0; ss < 8; ++ss) {
    int prow = (w << 4) + fr;
    bf16x8s ap = *(const bf16x8s*)(lds + prow * 512 +
                                   (((ss * 64) + (g << 4)) ^ ((prow & 7) << 4)));
#pragma unroll
    for (int d = 0; d < 4; ++d) {
      int dh = (d << 4) + fr;
      bf16x8s bv = *(const bf16x8s*)(lds + 32768 + dh * 512 +
                                     (((ss * 4 + g) ^ (dh & 7)) << 4));
      o4[d] = MFMA(ap, bv, o4[d], 0, 0, 0);
    }
  }
  u16* ob = O + (((long)bb * 8192 + n0 + (w << 4)) << 9) + (hh << 6);
#pragma unroll
  for (int d = 0; d < 4; ++d)
#pragma unroll
    for (int r = 0; r < 4; ++r) {
      int row = (g << 2) + r;
      int col = (d << 4) + fr;
      ob[((long)row << 9) + col] = f2b(o4[d][r] * li[r]);
    }
}

// ---------------- host ----------------
extern "C" void kernel_launch(void* const* d_in, const int* in_sizes, int n_in,
                              void* d_out, int out_size, void* d_ws, size_t ws_size,
                              hipStream_t stream) {
  const float* x = (const float*)d_in[0];
  const float* z = (const float*)d_in[1];
  const float* Wq = (const float*)d_in[2];
  const float* Wkv = (const float*)d_in[3];
  const float* Wo = (const float*)d_in[4];
  const float* bo = (const float*)d_in[5];
  float* out = (float*)d_out;

  char* base = (char*)d_ws;
  size_t off = 0;
  auto alloc = [&](size_t bytes) -> void* {
    void* r = base + off;
    off = (off + bytes + 255) & ~(size_t)255;
    return r;
  };
  u16* qb = (u16*)alloc(33554432);
  u16* kb = (u16*)alloc(16777216);
  u16* vtb = (u16*)alloc(16777216);
  u16* PS = (u16*)alloc(67108864);    // T1 partials, then pinv state (16 x 4MB)
  float* attn2 = (float*)alloc(8388608);
  u16* xb = (u16*)alloc(33554432);    // dead after qproj -> Ob
  u16* zb = (u16*)alloc(16777216);    // dead after kvproj -> attn2 split aN
  u16* wqt = (u16*)alloc(524288);
  u16* wkvt = (u16*)alloc(1048576);
  u16* wot = (u16*)alloc(524288);
  u16* qlh = (u16*)alloc(1048576);
  u16* qll = (u16*)alloc(1048576);
  u16* klh = (u16*)alloc(1048576);
  u16* kll = (u16*)alloc(1048576);
  u16* T1t = (u16*)alloc(2097152);
  u16* T2t = (u16*)alloc(1048576);    // T2^T [bh][64 dh][256 m]
  unsigned* cmax = (unsigned*)alloc(256);
  const long MC = 2097152;
  u16* P = PS;
  u16 *ztA_Nhi = P,          *ztA_Nlo = P + MC,      *ztA_Thi = P + 2 * MC,  *ztA_Tlo = P + 3 * MC;
  u16 *ztB_Nhi = P + 4 * MC,  *ztB_Nlo = P + 5 * MC,  *ztB_Thi = P + 6 * MC,  *ztB_Tlo = P + 7 * MC;
  u16 *az_Nhi = P + 8 * MC,   *az_Nlo = P + 9 * MC,   *az_Thi = P + 10 * MC,  *az_Tlo = P + 11 * MC;
  u16 *taThi = P + 12 * MC,   *taTlo = P + 13 * MC;
  u16 *tcThi = P + 14 * MC,   *tcTlo = P + 15 * MC;
  u16 *aNhi = zb, *aNlo = zb + MC;
  // T1 partials alias PS (consumed by merge before prep overwrites PS)
  float* opart = (float*)PS;                 // 8.4MB
  float* pm_ = opart + 2097152;
  float* pl_ = pm_ + 32768;
  u16* T1thi = T1t;
  u16* T1tlo = T1t + 524288;
  u16* Ob = xb;

  hipMemsetAsync(cmax, 0, 4, stream);
  k_f2b<<<16384, 256, 0, stream>>>(x, xb, 4194304);
  k_f2b<<<8192, 256, 0, stream>>>(z, zb, 2097152);
  k_wt<<<1024, 256, 0, stream>>>(Wq, wqt, 512);
  k_wt<<<2048, 256, 0, stream>>>(Wkv, wkvt, 1024);
  k_wt<<<1024, 256, 0, stream>>>(Wo, wot, 512);

  k_gemm128<0><<<dim3(4, 256), 256, 0, stream>>>(xb, wqt, qb, nullptr, nullptr,
                                                 nullptr, 512);
  k_gemm128<1><<<dim3(8, 128), 256, 0, stream>>>(zb, wkvt, kb, vtb, nullptr,
                                                 nullptr, 512);
  k_landmark<<<2048, 256, 0, stream>>>(qb, qlh, qll, 8192, 32, 1.f / 32.f);
  k_landmark<<<2048, 256, 0, stream>>>(kb, klh, kll, 4096, 16, 1.f / 16.f);

  k_sim2<<<dim3(4, 32), 256, 0, stream>>>(qlh, qll, klh, kll, attn2, aNhi, aNlo);
  k_colmax<<<32, 256, 0, stream>>>(attn2, cmax);

  k_t1part<<<512, 256, 0, stream>>>(qlh, kb, vtb, opart, pm_, pl_);
  k_t1merge<<<dim3(4, 32), 256, 0, stream>>>(opart, pm_, pl_, T1thi, T1tlo);

  k_prep_pinv<<<dim3(4, 4, 32), 256, 0, stream>>>(attn2, cmax, ztA_Nhi, ztA_Nlo,
                                                  ztA_Thi, ztA_Tlo);

  dim3 g256(4, 4, 32);
  u16 *cN0 = ztA_Nhi, *cN1 = ztA_Nlo, *cT0 = ztA_Thi, *cT1 = ztA_Tlo;
  u16 *nN0 = ztB_Nhi, *nN1 = ztB_Nlo, *nT0 = ztB_Thi, *nT1 = ztB_Tlo;
  for (int it = 0; it < 6; ++it) {
    bool last = (it == 5);
    // NS self-corrects: bf16-level error entering the last full-precision
    // iteration is contracted cubically. NP=1 for it<5, NP=3 for it=5.
    if (it < 5) {
      k_nn_mfma<1><<<g256, 256, 0, stream>>>(aNhi, aNlo, cT0, cT1, az_Nhi, az_Nlo,
                                             az_Thi, az_Tlo, 256, 1.f, 0.f, 0.f);
      k_nn_mfma<1><<<g256, 256, 0, stream>>>(az_Nhi, az_Nlo, az_Thi, az_Tlo, nullptr,
                                             nullptr, taThi, taTlo, 256, 1.f, -7.f, 15.f);
      k_nn_mfma<1><<<g256, 256, 0, stream>>>(az_Nhi, az_Nlo, taThi, taTlo, nullptr,
                                             nullptr, tcThi, tcTlo, 256, -1.f, 0.f, 13.f);
      k_nn_mfma<1><<<g256, 256, 0, stream>>>(cN0, cN1, tcThi, tcTlo, nN0, nN1,
                                             nT0, nT1, 256, 0.25f, 0.f, 0.f);
    } else {
      k_nn_mfma<3><<<g256, 256, 0, stream>>>(aNhi, aNlo, cT0, cT1, az_Nhi, az_Nlo,
                                             az_Thi, az_Tlo, 256, 1.f, 0.f, 0.f);
      k_nn_mfma<3><<<g256, 256, 0, stream>>>(az_Nhi, az_Nlo, az_Thi, az_Tlo, nullptr,
                                             nullptr, taThi, taTlo, 256, 1.f, -7.f, 15.f);
      k_nn_mfma<3><<<g256, 256, 0, stream>>>(az_Nhi, az_Nlo, taThi, taTlo, nullptr,
                                             nullptr, tcThi, tcTlo, 256, -1.f, 0.f, 13.f);
      k_nn_mfma<3><<<g256, 256, 0, stream>>>(cN0, cN1, tcThi, tcTlo, nN0, nN1,
                                             last ? nullptr : nT0, last ? nullptr : nT1,
                                             256, 0.25f, 0.f, 0.f);
    }
    u16* t0;
    t0 = cN0; cN0 = nN0; nN0 = t0;  t0 = cN1; cN1 = nN1; nN1 = t0;
    t0 = cT0; cT0 = nT0; nT0 = t0;  t0 = cT1; cT1 = nT1; nT1 = t0;
  }
  // T2^T = (pinv @ T1)^T, plain bf16, [bh][64 dh][256 m] via CT store
  k_nn_mfma<3><<<dim3(1, 4, 32), 256, 0, stream>>>(cN0, cN1, T1thi, T1tlo, nullptr,
                                                   nullptr, T2t, nullptr, 64,
                                                   1.f, 0.f, 0.f);

  k_fused_attn1<<<dim3(128, 32), 256, 0, stream>>>(qb, klh, T2t, Ob);
  k_gemm128<2><<<dim3(4, 256), 256, 0, stream>>>(Ob, wot, out, nullptr, x, bo, 512);
}

// Round 10
// 624.624 us; speedup vs baseline: 4.1287x; 1.0164x over previous
//
#include <hip/hip_runtime.h>

typedef unsigned short u16;
typedef __attribute__((ext_vector_type(8))) short bf16x8s;
typedef __attribute__((ext_vector_type(4))) float f32x4;

#define DEV static __device__ __forceinline__

DEV float b2f(u16 v) { return __uint_as_float(((unsigned)v) << 16); }
// HW RNE f32->bf16 (1 VALU op; bit-identical to the old 4-op manual RNE)
DEV u16 f2b(float f) {
  unsigned r;
  asm("v_cvt_pk_bf16_f32 %0, %1, %1" : "=v"(r) : "v"(f));
  return (u16)r;
}
// packed: low16 = rne(a), high16 = rne(b)
DEV unsigned f2b2(float a, float b) {
  unsigned r;
  asm("v_cvt_pk_bf16_f32 %0, %1, %2" : "=v"(r) : "v"(a), "v"(b));
  return r;
}

// async global->LDS, 16B per lane; lds base must be wave-uniform (HW adds lane*16)
#define GLL(gp, lp)                                                            \
  __builtin_amdgcn_global_load_lds(                                            \
      (const __attribute__((address_space(1))) unsigned int*)(gp),             \
      (__attribute__((address_space(3))) unsigned int*)(lp), 16, 0, 0)

#define MFMA __builtin_amdgcn_mfma_f32_16x16x32_bf16

// ---------------- fused converts: x and z fp32 -> bf16 ----------------------
__global__ __launch_bounds__(256) void k_f2bxz(const float* __restrict__ x,
                                               const float* __restrict__ z,
                                               u16* __restrict__ xb,
                                               u16* __restrict__ zb) {
  long i = (long)blockIdx.x * 256 + threadIdx.x;  // < 6291456
  const float* src;
  u16* dst;
  long j;
  if (i < 4194304) { src = x; dst = xb; j = i; }
  else { src = z; dst = zb; j = i - 4194304; }
  float4 v = *(const float4*)(src + j * 4);
  unsigned* d = (unsigned*)(dst + j * 4);
  d[0] = f2b2(v.x, v.y);
  d[1] = f2b2(v.z, v.w);
}

// ---------------- fused weight transposes: Wq, Wkv, Wo ----------------------
__global__ __launch_bounds__(256) void k_wt3(const float* __restrict__ Wq,
                                             const float* __restrict__ Wkv,
                                             const float* __restrict__ Wo,
                                             u16* __restrict__ wqt,
                                             u16* __restrict__ wkvt,
                                             u16* __restrict__ wot) {
  int e = blockIdx.x * 256 + threadIdx.x;  // < 1048576
  const float* W;
  u16* Wt;
  int N, le;
  if (e < 262144) { W = Wq; Wt = wqt; N = 512; le = e; }
  else if (e < 786432) { W = Wkv; Wt = wkvt; N = 1024; le = e - 262144; }
  else { W = Wo; Wt = wot; N = 512; le = e - 786432; }
  int nn = le >> 9, kk = le & 511;
  Wt[le] = f2b(W[(long)kk * N + nn]);
}

// ---------------- 128x128 bf16 NT GEMM (BK=64, global_load_lds, swizzled) ----
template <int MODE>
__global__ __launch_bounds__(256, 2) void k_gemm128(
    const u16* __restrict__ A, const u16* __restrict__ Bm, void* __restrict__ C0,
    void* __restrict__ C1, const float* __restrict__ xres,
    const float* __restrict__ bias, int K) {
  const int nwg = gridDim.x * gridDim.y;
  const int orig = blockIdx.y * gridDim.x + blockIdx.x;
  const int qq = nwg >> 3, rr = nwg & 7;
  const int xcd = orig & 7, loc = orig >> 3;
  const int swz = (xcd < rr ? xcd * (qq + 1) : rr * (qq + 1) + (xcd - rr) * qq) + loc;
  const int m0 = (swz / gridDim.x) << 7, n0 = (swz % gridDim.x) << 7;
  const int t = threadIdx.x, lane = t & 63, w = t >> 6;
  const int wm = (w >> 1) << 6, wn = (w & 1) << 6;
  const int fr = lane & 15, g = lane >> 4;
  __shared__ u16 As[8192];
  __shared__ u16 Bs[8192];
  f32x4 acc[4][4] = {};
  const int srow = t >> 3, scs = t & 7;
  for (int k0 = 0; k0 < K; k0 += 64) {
    __syncthreads();
#pragma unroll
    for (int i = 0; i < 4; ++i) {
      int row = srow + (i << 5), cs = scs;
      GLL(A + (long)(m0 + row) * K + k0 + ((cs ^ (row & 7)) << 3),
          &As[(i << 11) + (w << 9)]);
      GLL(Bm + (long)(n0 + row) * K + k0 + ((cs ^ (row & 7)) << 3),
          &Bs[(i << 11) + (w << 9)]);
    }
    __syncthreads();
#pragma unroll
    for (int ks = 0; ks < 2; ++ks) {
      bf16x8s af[4], bf[4];
#pragma unroll
      for (int fi = 0; fi < 4; ++fi) {
        int row = wm + fi * 16 + fr;
        af[fi] = *(const bf16x8s*)((const char*)As + row * 128 +
                                   (((ks * 4 + g) ^ (row & 7)) << 4));
      }
#pragma unroll
      for (int fj = 0; fj < 4; ++fj) {
        int row = wn + fj * 16 + fr;
        bf[fj] = *(const bf16x8s*)((const char*)Bs + row * 128 +
                                   (((ks * 4 + g) ^ (row & 7)) << 4));
      }
#pragma unroll
      for (int fi = 0; fi < 4; ++fi)
#pragma unroll
        for (int fj = 0; fj < 4; ++fj)
          acc[fi][fj] = MFMA(af[fi], bf[fj], acc[fi][fj], 0, 0, 0);
    }
  }
  const int crow = g << 2;
#pragma unroll
  for (int fi = 0; fi < 4; ++fi)
#pragma unroll
    for (int fj = 0; fj < 4; ++fj)
#pragma unroll
      for (int r = 0; r < 4; ++r) {
        int row = m0 + wm + fi * 16 + crow + r;
        int col = n0 + wn + fj * 16 + fr;
        float v = acc[fi][fj][r];
        if (MODE == 0) {
          int b = row >> 13, n = row & 8191, h = col >> 6, dh = col & 63;
          ((u16*)C0)[((((long)(b * 8 + h)) << 13) + n) * 64 + dh] = f2b(v * 0.125f);
        } else if (MODE == 1) {
          int b = row >> 12, nz = row & 4095;
          if (col < 512) {
            int h = col >> 6, dh = col & 63;
            ((u16*)C0)[((((long)(b * 8 + h)) << 12) + nz) * 64 + dh] = f2b(v);
          } else {
            int c2 = col - 512, h = c2 >> 6, dh = c2 & 63;
            ((u16*)C1)[((((long)(b * 8 + h) * 64 + dh)) << 12) + nz] = f2b(v);
          }
        } else if (MODE == 2) {
          long idx = ((long)row << 9) + col;
          ((float*)C0)[idx] = v + xres[idx] + bias[col];
        }
      }
}

// ---------------- fused landmarks (q then k): mean -> split hi/lo bf16 ------
__global__ __launch_bounds__(256) void k_land2(const u16* __restrict__ qb,
                                               const u16* __restrict__ kb,
                                               u16* __restrict__ qlh,
                                               u16* __restrict__ qll,
                                               u16* __restrict__ klh,
                                               u16* __restrict__ kll) {
  int pidx = blockIdx.x * 4 + (threadIdx.x >> 6);  // < 16384
  const u16* src;
  u16 *hi, *lo;
  int ntok, l;
  float inv;
  if (pidx < 8192) { src = qb; hi = qlh; lo = qll; ntok = 8192; l = 32; inv = 1.f / 32.f; }
  else { src = kb; hi = klh; lo = kll; ntok = 4096; l = 16; inv = 1.f / 16.f; pidx -= 8192; }
  int d = threadIdx.x & 63;
  int bh = pidx >> 8, m = pidx & 255;
  const u16* s = src + ((long)bh * ntok + (long)m * l) * 64 + d;
  float sum = 0.f;
  for (int j = 0; j < l; ++j) sum += b2f(s[j * 64]);
  sum *= inv;
  long o = ((long)bh * 256 + m) * 64 + d;
  u16 h = f2b(sum);
  hi[o] = h;
  lo[o] = f2b(sum - b2f(h));
}

// ---------------- sim2 + softmax via split-bf16 MFMA ------------------------
__global__ __launch_bounds__(256, 2) void k_sim2(
    const u16* __restrict__ qlh, const u16* __restrict__ qll,
    const u16* __restrict__ klh, const u16* __restrict__ kll,
    float* __restrict__ attn2, u16* __restrict__ aNhi, u16* __restrict__ aNlo) {
  const int rb = blockIdx.x, bh = blockIdx.y;
  const int t = threadIdx.x, lane = t & 63, w = t >> 6;
  const int fr = lane & 15, g = lane >> 4;
  __shared__ char lds[65536];  // [0,32K) k_land hi ; [32K,64K) k_land lo
  {
    const u16* kh = klh + (long)bh * 16384;
    const u16* kl = kll + (long)bh * 16384;
    int srow8 = lane >> 3, cs7 = lane & 7;
#pragma unroll
    for (int i = 0; i < 8; ++i) {
      int slab = w * 8 + i;
      int krow = slab * 8 + srow8;
      GLL(kh + krow * 64 + ((cs7 ^ (krow & 7)) << 3), lds + slab * 1024);
      GLL(kl + krow * 64 + ((cs7 ^ (krow & 7)) << 3), lds + 32768 + slab * 1024);
    }
  }
  long qoff = ((long)bh * 256 + rb * 64 + w * 16 + fr) * 64;
  bf16x8s qh0 = *(const bf16x8s*)(qlh + qoff + g * 8);
  bf16x8s qh1 = *(const bf16x8s*)(qlh + qoff + 32 + g * 8);
  bf16x8s ql0 = *(const bf16x8s*)(qll + qoff + g * 8);
  bf16x8s ql1 = *(const bf16x8s*)(qll + qoff + 32 + g * 8);
  __syncthreads();
  f32x4 s[16];
#pragma unroll
  for (int c = 0; c < 16; ++c) {
    int j = (c << 4) + fr;
    int o0 = j * 128 + ((g ^ (j & 7)) << 4);
    int o1 = j * 128 + (((4 + g) ^ (j & 7)) << 4);
    bf16x8s kh0 = *(const bf16x8s*)(lds + o0);
    bf16x8s kh1 = *(const bf16x8s*)(lds + o1);
    bf16x8s kl0 = *(const bf16x8s*)(lds + 32768 + o0);
    bf16x8s kl1 = *(const bf16x8s*)(lds + 32768 + o1);
    f32x4 zz = {};
    zz = MFMA(qh0, kh0, zz, 0, 0, 0);
    zz = MFMA(qh1, kh1, zz, 0, 0, 0);
    zz = MFMA(qh0, kl0, zz, 0, 0, 0);
    zz = MFMA(qh1, kl1, zz, 0, 0, 0);
    zz = MFMA(ql0, kh0, zz, 0, 0, 0);
    zz = MFMA(ql1, kh1, zz, 0, 0, 0);
    s[c] = zz;
  }
  float li[4];
#pragma unroll
  for (int r = 0; r < 4; ++r) {
    float m = s[0][r];
#pragma unroll
    for (int c = 1; c < 16; ++c) m = fmaxf(m, s[c][r]);
    m = fmaxf(m, __shfl_xor(m, 1, 64));
    m = fmaxf(m, __shfl_xor(m, 2, 64));
    m = fmaxf(m, __shfl_xor(m, 4, 64));
    m = fmaxf(m, __shfl_xor(m, 8, 64));
    float l = 0.f;
#pragma unroll
    for (int c = 0; c < 16; ++c) {
      float e = __expf(s[c][r] - m);
      s[c][r] = e;
      l += e;
    }
    l += __shfl_xor(l, 1, 64);
    l += __shfl_xor(l, 2, 64);
    l += __shfl_xor(l, 4, 64);
    l += __shfl_xor(l, 8, 64);
    li[r] = 1.f / l;
  }
#pragma unroll
  for (int c = 0; c < 16; ++c)
#pragma unroll
    for (int r = 0; r < 4; ++r) {
      int row = rb * 64 + w * 16 + (g << 2) + r;
      int col = (c << 4) + fr;
      long idx = ((long)bh << 16) + ((long)row << 8) + col;
      float p = s[c][r] * li[r];
      attn2[idx] = p;
      u16 h = f2b(p);
      aNhi[idx] = h;
      aNlo[idx] = f2b(p - b2f(h));
    }
}

__global__ __launch_bounds__(256) void k_colmax(const float* __restrict__ attn2,
                                                unsigned* __restrict__ cmax) {
  int bh = blockIdx.x, j = threadIdx.x, lane = j & 63, w = j >> 6;
  const float* p = attn2 + ((long)bh << 16) + j;
  float s = 0.f;
  for (int m = 0; m < 256; ++m) s += p[m * 256];
  float mx = s;
  for (int o = 1; o < 64; o <<= 1) mx = fmaxf(mx, __shfl_xor(mx, o, 64));
  __shared__ float r1[4];
  if (lane == 0) r1[w] = mx;
  __syncthreads();
  if (j == 0) {
    mx = fmaxf(fmaxf(r1[0], r1[1]), fmaxf(r1[2], r1[3]));
    atomicMax(cmax, __float_as_uint(mx));
  }
}

// ---------------- T1 split-KV partial: (bh, rb, kc of 1024 keys) ------------
__global__ __launch_bounds__(256, 2) void k_t1part(
    const u16* __restrict__ qlb, const u16* __restrict__ kb,
    const u16* __restrict__ vtb, float* __restrict__ opart,
    float* __restrict__ pm_, float* __restrict__ pl_) {
  int orig = blockIdx.x;  // 512 = 32 bh * 4 kc * 4 rb
  int xcd = orig & 7, idx = orig >> 3;
  int p = xcd * 16 + (idx >> 2);  // (bh,kc) pair; 4 rb of a pair share an XCD
  int rb = idx & 3;
  int bh = p >> 2, kc = p & 3;
  const int t = threadIdx.x, lane = t & 63, w = t >> 6;
  const int fr = lane & 15, g = lane >> 4;
  __shared__ char lds[65536];  // [0,32K) K chunk (aliased by P); [32K,64K) V^T
  const u16* qrow = qlb + ((long)bh * 256 + rb * 64 + w * 16 + fr) * 64;
  bf16x8s qa0 = *(const bf16x8s*)(qrow + g * 8);
  bf16x8s qa1 = *(const bf16x8s*)(qrow + 32 + g * 8);
  f32x4 o[4] = {};
  float m[4] = {-3e38f, -3e38f, -3e38f, -3e38f};
  float l[4] = {};
  const long kbase = (long)bh * 262144;
  for (int cc = 0; cc < 4; ++cc) {
    int c0 = kc * 1024 + cc * 256;
    __syncthreads();
#pragma unroll
    for (int i = 0; i < 8; ++i) {
      int seg = (i << 8) + t, row = seg >> 3, cs = seg & 7;
      GLL(kb + kbase + (long)(c0 + row) * 64 + ((cs ^ (row & 7)) << 3),
          lds + (i << 12) + (w << 10));
    }
#pragma unroll
    for (int i = 0; i < 8; ++i) {
      int seg = (i << 8) + t, row = seg >> 5, cs = seg & 31;
      GLL(vtb + kbase + (long)row * 4096 + c0 + ((cs ^ (row & 7)) << 3),
          lds + 32768 + (i << 12) + (w << 10));
    }
    __syncthreads();
    f32x4 s[16];
#pragma unroll
    for (int c = 0; c < 16; ++c) {
      int j = c * 16 + fr;
      bf16x8s b0 = *(const bf16x8s*)(lds + j * 128 + ((g ^ (j & 7)) << 4));
      bf16x8s b1 = *(const bf16x8s*)(lds + j * 128 + (((4 + g) ^ (j & 7)) << 4));
      f32x4 zz = {};
      zz = MFMA(qa0, b0, zz, 0, 0, 0);
      zz = MFMA(qa1, b1, zz, 0, 0, 0);
      s[c] = zz;
    }
    float sc[4];
#pragma unroll
    for (int r = 0; r < 4; ++r) {
      float pm = s[0][r];
#pragma unroll
      for (int c = 1; c < 16; ++c) pm = fmaxf(pm, s[c][r]);
      pm = fmaxf(pm, __shfl_xor(pm, 1, 64));
      pm = fmaxf(pm, __shfl_xor(pm, 2, 64));
      pm = fmaxf(pm, __shfl_xor(pm, 4, 64));
      pm = fmaxf(pm, __shfl_xor(pm, 8, 64));
      float mn = fmaxf(m[r], pm);
      sc[r] = __expf(m[r] - mn);
      m[r] = mn;
    }
#pragma unroll
    for (int r = 0; r < 4; ++r) {
      float su = 0.f;
#pragma unroll
      for (int c = 0; c < 16; ++c) {
        float e = __expf(s[c][r] - m[r]);
        s[c][r] = e;
        su += e;
      }
      su += __shfl_xor(su, 1, 64);
      su += __shfl_xor(su, 2, 64);
      su += __shfl_xor(su, 4, 64);
      su += __shfl_xor(su, 8, 64);
      l[r] = l[r] * sc[r] + su;
    }
#pragma unroll
    for (int d = 0; d < 4; ++d)
#pragma unroll
      for (int r = 0; r < 4; ++r) o[d][r] *= sc[r];
    __syncthreads();
#pragma unroll
    for (int c = 0; c < 16; ++c)
#pragma unroll
      for (int r = 0; r < 4; ++r) {
        int row = (w << 4) + (g << 2) + r;
        int byin = (c << 5) + (fr << 1);
        *(u16*)(lds + row * 512 + (byin ^ ((row & 7) << 4))) = f2b(s[c][r]);
      }
    asm volatile("s_waitcnt lgkmcnt(0)" ::: "memory");
    __builtin_amdgcn_sched_barrier(0);
#pragma unroll
    for (int ss = 0; ss < 8; ++ss) {
      int prow = (w << 4) + fr;
      bf16x8s ap = *(const bf16x8s*)(lds + prow * 512 +
                                     (((ss * 64) + (g << 4)) ^ ((prow & 7) << 4)));
#pragma unroll
      for (int d = 0; d < 4; ++d) {
        int dh = (d << 4) + fr;
        bf16x8s bv = *(const bf16x8s*)(lds + 32768 + dh * 512 +
                                       (((ss * 4 + g) ^ (dh & 7)) << 4));
        o[d] = MFMA(ap, bv, o[d], 0, 0, 0);
      }
    }
  }
  // LDS-transpose o then coalesced float4 writes
  __syncthreads();
  float* lf = (float*)lds;
#pragma unroll
  for (int d = 0; d < 4; ++d)
#pragma unroll
    for (int r = 0; r < 4; ++r)
      lf[((w << 4) + (g << 2) + r) * 76 + (d << 4) + fr] = o[d][r];
  __syncthreads();
  const long pb = (long)(bh * 4 + kc) * 256 + rb * 64;
#pragma unroll
  for (int i = 0; i < 4; ++i) {
    int row = i * 16 + (t >> 4);
    int c4 = (t & 15) << 2;
    float4 v = *(const float4*)&lf[row * 76 + c4];
    *(float4*)&opart[(pb + row) * 64 + c4] = v;
  }
  if (fr == 0) {
#pragma unroll
    for (int r = 0; r < 4; ++r) {
      int lr = (w << 4) + (g << 2) + r;
      pm_[pb + lr] = m[r];
      pl_[pb + lr] = l[r];
    }
  }
}

// ---------------- merge 4 partials -> T1^T split bf16 -----------------------
__global__ __launch_bounds__(256) void k_t1merge(
    const float* __restrict__ opart, const float* __restrict__ pm_,
    const float* __restrict__ pl_, u16* __restrict__ T1thi,
    u16* __restrict__ T1tlo) {
  const int rb = blockIdx.x, bh = blockIdx.y;
  const int t = threadIdx.x;
#pragma unroll
  for (int rp = 0; rp < 4; ++rp) {
    int row = rb * 64 + rp * 16 + (t >> 4);
    int dh4 = (t & 15) << 2;
    float pmv[4], M = -3e38f;
#pragma unroll
    for (int i = 0; i < 4; ++i) {
      pmv[i] = pm_[(long)(bh * 4 + i) * 256 + row];
      M = fmaxf(M, pmv[i]);
    }
    float L = 0.f, wt[4];
#pragma unroll
    for (int i = 0; i < 4; ++i) {
      wt[i] = __expf(pmv[i] - M);
      L += pl_[(long)(bh * 4 + i) * 256 + row] * wt[i];
    }
    float4 acc = {0.f, 0.f, 0.f, 0.f};
#pragma unroll
    for (int i = 0; i < 4; ++i) {
      float4 v = *(const float4*)&opart[((long)(bh * 4 + i) * 256 + row) * 64 + dh4];
      acc.x += v.x * wt[i]; acc.y += v.y * wt[i];
      acc.z += v.z * wt[i]; acc.w += v.w * wt[i];
    }
    float invL = 1.f / L;
    float vv[4] = {acc.x * invL, acc.y * invL, acc.z * invL, acc.w * invL};
#pragma unroll
    for (int e = 0; e < 4; ++e) {
      int dh = dh4 + e;
      long idx = (long)bh * 16384 + (long)dh * 256 + row;
      u16 h = f2b(vv[e]);
      T1thi[idx] = h;
      T1tlo[idx] = f2b(vv[e] - b2f(h));
    }
  }
}

// ---------------- MFMA NN GEMM (pinv chain); NP=1 plain bf16, NP=3 split ----
template <int NP>
__global__ __launch_bounds__(256) void k_nn_mfma(
    const u16* __restrict__ Ahi, const u16* __restrict__ Alo,
    const u16* __restrict__ Bthi, const u16* __restrict__ Btlo,
    u16* __restrict__ CNhi, u16* __restrict__ CNlo,
    u16* __restrict__ CThi, u16* __restrict__ CTlo,
    int Nc, float sab, float sa, float cdiag) {
  const int bz = blockIdx.z;
  const long offA = (long)bz << 16;
  const long offB = (long)bz * ((long)Nc << 8);
  const int m0 = blockIdx.y << 6, n0 = blockIdx.x << 6;
  const int t = threadIdx.x, lane = t & 63, w = t >> 6;
  const int wm = (w >> 1) << 5, wn = (w & 1) << 5;
  const int fr = lane & 15, g = lane >> 4;
  __shared__ u16 lds[16384];
  u16* LAh = lds;
  u16* LAl = lds + 4096;
  u16* LBh = lds + 8192;
  u16* LBl = lds + 12288;
  f32x4 acc[2][2] = {};
  const int srow8 = lane >> 3, cs = lane & 7;
  for (int k0 = 0; k0 < 256; k0 += 64) {
    __syncthreads();
#pragma unroll
    for (int j = 0; j < 2; ++j) {
      int slab = w * 2 + j;
      int row = slab * 8 + srow8;
      long asrc = offA + (long)(m0 + row) * 256 + k0 + ((cs ^ (row & 7)) << 3);
      long bsrc = offB + (long)(n0 + row) * 256 + k0 + ((cs ^ (row & 7)) << 3);
      GLL(Ahi + asrc, LAh + slab * 512);
      GLL(Bthi + bsrc, LBh + slab * 512);
      if (NP == 3) {
        GLL(Alo + asrc, LAl + slab * 512);
        GLL(Btlo + bsrc, LBl + slab * 512);
      }
    }
    __syncthreads();
#pragma unroll
    for (int ks = 0; ks < 2; ++ks) {
      const int ra0 = wm + fr, ra1 = wm + 16 + fr;
      const int rb0 = wn + fr, rb1 = wn + 16 + fr;
#define RD(base, row) \
  (*(const bf16x8s*)((const char*)(base) + (row) * 128 + (((ks * 4 + g) ^ ((row) & 7)) << 4)))
      bf16x8s ah0 = RD(LAh, ra0), ah1 = RD(LAh, ra1);
      bf16x8s bh0 = RD(LBh, rb0), bh1 = RD(LBh, rb1);
      acc[0][0] = MFMA(ah0, bh0, acc[0][0], 0, 0, 0);
      acc[0][1] = MFMA(ah0, bh1, acc[0][1], 0, 0, 0);
      acc[1][0] = MFMA(ah1, bh0, acc[1][0], 0, 0, 0);
      acc[1][1] = MFMA(ah1, bh1, acc[1][1], 0, 0, 0);
      if (NP == 3) {
        bf16x8s al0 = RD(LAl, ra0), al1 = RD(LAl, ra1);
        bf16x8s bl0 = RD(LBl, rb0), bl1 = RD(LBl, rb1);
        acc[0][0] = MFMA(ah0, bl0, acc[0][0], 0, 0, 0);
        acc[0][0] = MFMA(al0, bh0, acc[0][0], 0, 0, 0);
        acc[0][1] = MFMA(ah0, bl1, acc[0][1], 0, 0, 0);
        acc[0][1] = MFMA(al0, bh1, acc[0][1], 0, 0, 0);
        acc[1][0] = MFMA(ah1, bl0, acc[1][0], 0, 0, 0);
        acc[1][0] = MFMA(al1, bh0, acc[1][0], 0, 0, 0);
        acc[1][1] = MFMA(ah1, bl1, acc[1][1], 0, 0, 0);
        acc[1][1] = MFMA(al1, bh1, acc[1][1], 0, 0, 0);
      }
#undef RD
    }
  }
  const int crow = g << 2;
  const long offC = (long)bz * ((long)Nc << 8);
#pragma unroll
  for (int i = 0; i < 2; ++i)
#pragma unroll
    for (int j = 0; j < 2; ++j)
#pragma unroll
      for (int r = 0; r < 4; ++r) {
        int row = m0 + wm + i * 16 + crow + r;
        int col = n0 + wn + j * 16 + fr;
        float v = sab * acc[i][j][r];
        if (sa != 0.f) {
          long ai = offA + ((long)row << 8) + col;
          v += sa * (b2f(Ahi[ai]) + b2f(Alo[ai]));
        }
        if (row == col) v += cdiag;
        if (CNhi) {
          long ci = offC + (long)row * Nc + col;
          u16 h = f2b(v);
          if (CNlo) { CNhi[ci] = h; CNlo[ci] = f2b(v - b2f(h)); }
          else CNhi[ci] = h;
        }
        if (CThi) {
          long ti = offC + ((long)col << 8) + row;
          u16 h = f2b(v);
          CThi[ti] = h;
          if (CTlo) CTlo[ti] = f2b(v - b2f(h));
        }
      }
}

// ---------------- pinv operand prep (z0 only; aN written by k_sim2) ---------
__global__ __launch_bounds__(256) void k_prep_pinv(
    const float* __restrict__ attn2, const unsigned* __restrict__ cmax,
    u16* __restrict__ zNhi, u16* __restrict__ zNlo,
    u16* __restrict__ zThi, u16* __restrict__ zTlo) {
  const int bz = blockIdx.z, i0 = blockIdx.y << 6, j0 = blockIdx.x << 6;
  const float s = 1.f / __uint_as_float(*cmax);
  const float* base = attn2 + ((long)bz << 16);
  __shared__ float mt[64][65];
  const int r = threadIdx.x >> 2, cb = (threadIdx.x & 3) << 4;
#pragma unroll
  for (int c4 = 0; c4 < 16; c4 += 4) {
    float4 v = *(const float4*)&base[(long)(j0 + r) * 256 + i0 + cb + c4];
    mt[r][cb + c4] = v.x; mt[r][cb + c4 + 1] = v.y;
    mt[r][cb + c4 + 2] = v.z; mt[r][cb + c4 + 3] = v.w;
  }
  __syncthreads();
  const int i = i0 + r;
#pragma unroll
  for (int c4 = 0; c4 < 16; c4 += 4) {
    float4 v = *(const float4*)&base[(long)i * 256 + j0 + cb + c4];
    float vv[4] = {v.x, v.y, v.z, v.w};
#pragma unroll
    for (int e = 0; e < 4; ++e) {
      int j = j0 + cb + c4 + e;
      long idx = ((long)bz << 16) + ((long)i << 8) + j;
      float zt = vv[e] * s;
      u16 zh = f2b(zt);
      zThi[idx] = zh; zTlo[idx] = f2b(zt - b2f(zh));
      float zn = mt[cb + c4 + e][r] * s;
      u16 nh = f2b(zn);
      zNhi[idx] = nh; zNlo[idx] = f2b(zn - b2f(nh));
    }
  }
}

// ---------------- fused sim1: O = softmax(q @ k_land^T) @ T2 ----------------
__global__ __launch_bounds__(256) void k_fused_attn1(const u16* __restrict__ q,
                                                     const u16* __restrict__ klb,
                                                     const u16* __restrict__ t2t,
                                                     u16* __restrict__ O) {
  const int bh = blockIdx.y, n0 = blockIdx.x << 6;
  const int bb = bh >> 3, hh = bh & 7;
  const int t = threadIdx.x, lane = t & 63, w = t >> 6;
  const int fr = lane & 15, g = lane >> 4;
  __shared__ char lds[65536];
  {
    const u16* ks = klb + (long)bh * 16384;
    const u16* ts = t2t + (long)bh * 16384;
    int srow8 = lane >> 3, cs7 = lane & 7;
    int srow2 = lane >> 5, seg32 = lane & 31;
#pragma unroll
    for (int i = 0; i < 8; ++i) {
      int slab = w * 8 + i;
      int krow = slab * 8 + srow8;
      GLL(ks + krow * 64 + ((cs7 ^ (krow & 7)) << 3), lds + slab * 1024);
      int trow = slab * 2 + srow2;
      GLL(ts + trow * 256 + ((seg32 ^ (trow & 7)) << 3), lds + 32768 + slab * 1024);
    }
  }
  __syncthreads();
  const u16* qrow = q + ((long)bh * 8192 + n0 + (w << 4) + fr) * 64;
  bf16x8s qa0 = *(const bf16x8s*)(qrow + g * 8);
  bf16x8s qa1 = *(const bf16x8s*)(qrow + 32 + g * 8);
  f32x4 s[16];
#pragma unroll
  for (int c = 0; c < 16; ++c) {
    int j = (c << 4) + fr;
    bf16x8s b0 = *(const bf16x8s*)(lds + j * 128 + ((g ^ (j & 7)) << 4));
    bf16x8s b1 = *(const bf16x8s*)(lds + j * 128 + (((4 + g) ^ (j & 7)) << 4));
    f32x4 zz = {};
    zz = MFMA(qa0, b0, zz, 0, 0, 0);
    zz = MFMA(qa1, b1, zz, 0, 0, 0);
    s[c] = zz;
  }
  float li[4];
#pragma unroll
  for (int r = 0; r < 4; ++r) {
    float m = s[0][r];
#pragma unroll
    for (int c = 1; c < 16; ++c) m = fmaxf(m, s[c][r]);
    m = fmaxf(m, __shfl_xor(m, 1, 64));
    m = fmaxf(m, __shfl_xor(m, 2, 64));
    m = fmaxf(m, __shfl_xor(m, 4, 64));
    m = fmaxf(m, __shfl_xor(m, 8, 64));
    float l = 0.f;
#pragma unroll
    for (int c = 0; c < 16; ++c) {
      float e = __expf(s[c][r] - m);
      s[c][r] = e;
      l += e;
    }
    l += __shfl_xor(l, 1, 64);
    l += __shfl_xor(l, 2, 64);
    l += __shfl_xor(l, 4, 64);
    l += __shfl_xor(l, 8, 64);
    li[r] = 1.f / l;
  }
  __syncthreads();  // all waves done reading k_land; reuse region as P[64][256]
#pragma unroll
  for (int c = 0; c < 16; ++c)
#pragma unroll
    for (int r = 0; r < 4; ++r) {
      int row = (w << 4) + (g << 2) + r;
      int byin = (c << 5) + (fr << 1);
      *(u16*)(lds + row * 512 + (byin ^ ((row & 7) << 4))) = f2b(s[c][r]);
    }
  asm volatile("s_waitcnt lgkmcnt(0)" ::: "memory");
  __builtin_amdgcn_sched_barrier(0);
  f32x4 o4[4] = {};
#pragma unroll
  for (int ss = 0; ss < 8; ++ss) {
    int prow = (w << 4) + fr;
    bf16x8s ap = *(const bf16x8s*)(lds + prow * 512 +
                                   (((ss * 64) + (g << 4)) ^ ((prow & 7) << 4)));
#pragma unroll
    for (int d = 0; d < 4; ++d) {
      int dh = (d << 4) + fr;
      bf16x8s bv = *(const bf16x8s*)(lds + 32768 + dh * 512 +
                                     (((ss * 4 + g) ^ (dh & 7)) << 4));
      o4[d] = MFMA(ap, bv, o4[d], 0, 0, 0);
    }
  }
  u16* ob = O + (((long)bb * 8192 + n0 + (w << 4)) << 9) + (hh << 6);
#pragma unroll
  for (int d = 0; d < 4; ++d)
#pragma unroll
    for (int r = 0; r < 4; ++r) {
      int row = (g << 2) + r;
      int col = (d << 4) + fr;
      ob[((long)row << 9) + col] = f2b(o4[d][r] * li[r]);
    }
}

// ---------------- host ----------------
extern "C" void kernel_launch(void* const* d_in, const int* in_sizes, int n_in,
                              void* d_out, int out_size, void* d_ws, size_t ws_size,
                              hipStream_t stream) {
  const float* x = (const float*)d_in[0];
  const float* z = (const float*)d_in[1];
  const float* Wq = (const float*)d_in[2];
  const float* Wkv = (const float*)d_in[3];
  const float* Wo = (const float*)d_in[4];
  const float* bo = (const float*)d_in[5];
  float* out = (float*)d_out;

  char* base = (char*)d_ws;
  size_t off = 0;
  auto alloc = [&](size_t bytes) -> void* {
    void* r = base + off;
    off = (off + bytes + 255) & ~(size_t)255;
    return r;
  };
  u16* qb = (u16*)alloc(33554432);
  u16* kb = (u16*)alloc(16777216);
  u16* vtb = (u16*)alloc(16777216);
  u16* PS = (u16*)alloc(67108864);    // T1 partials, then pinv state (16 x 4MB)
  float* attn2 = (float*)alloc(8388608);
  u16* xb = (u16*)alloc(33554432);    // dead after qproj -> Ob
  u16* zb = (u16*)alloc(16777216);    // dead after kvproj -> attn2 split aN
  u16* wqt = (u16*)alloc(524288);
  u16* wkvt = (u16*)alloc(1048576);
  u16* wot = (u16*)alloc(524288);
  u16* qlh = (u16*)alloc(1048576);
  u16* qll = (u16*)alloc(1048576);
  u16* klh = (u16*)alloc(1048576);
  u16* kll = (u16*)alloc(1048576);
  u16* T1t = (u16*)alloc(2097152);
  u16* T2t = (u16*)alloc(1048576);    // T2^T [bh][64 dh][256 m]
  unsigned* cmax = (unsigned*)alloc(256);
  const long MC = 2097152;
  u16* P = PS;
  u16 *ztA_Nhi = P,          *ztA_Nlo = P + MC,      *ztA_Thi = P + 2 * MC,  *ztA_Tlo = P + 3 * MC;
  u16 *ztB_Nhi = P + 4 * MC,  *ztB_Nlo = P + 5 * MC,  *ztB_Thi = P + 6 * MC,  *ztB_Tlo = P + 7 * MC;
  u16 *az_Nhi = P + 8 * MC,   *az_Nlo = P + 9 * MC,   *az_Thi = P + 10 * MC,  *az_Tlo = P + 11 * MC;
  u16 *taThi = P + 12 * MC,   *taTlo = P + 13 * MC;
  u16 *tcThi = P + 14 * MC,   *tcTlo = P + 15 * MC;
  u16 *aNhi = zb, *aNlo = zb + MC;
  // T1 partials alias PS (consumed by merge before prep overwrites PS)
  float* opart = (float*)PS;                 // 8.4MB
  float* pm_ = opart + 2097152;
  float* pl_ = pm_ + 32768;
  u16* T1thi = T1t;
  u16* T1tlo = T1t + 524288;
  u16* Ob = xb;

  hipMemsetAsync(cmax, 0, 4, stream);
  k_f2bxz<<<24576, 256, 0, stream>>>(x, z, xb, zb);
  k_wt3<<<4096, 256, 0, stream>>>(Wq, Wkv, Wo, wqt, wkvt, wot);

  k_gemm128<0><<<dim3(4, 256), 256, 0, stream>>>(xb, wqt, qb, nullptr, nullptr,
                                                 nullptr, 512);
  k_gemm128<1><<<dim3(8, 128), 256, 0, stream>>>(zb, wkvt, kb, vtb, nullptr,
                                                 nullptr, 512);
  k_land2<<<4096, 256, 0, stream>>>(qb, kb, qlh, qll, klh, kll);

  k_sim2<<<dim3(4, 32), 256, 0, stream>>>(qlh, qll, klh, kll, attn2, aNhi, aNlo);
  k_colmax<<<32, 256, 0, stream>>>(attn2, cmax);

  k_t1part<<<512, 256, 0, stream>>>(qlh, kb, vtb, opart, pm_, pl_);
  k_t1merge<<<dim3(4, 32), 256, 0, stream>>>(opart, pm_, pl_, T1thi, T1tlo);

  k_prep_pinv<<<dim3(4, 4, 32), 256, 0, stream>>>(attn2, cmax, ztA_Nhi, ztA_Nlo,
                                                  ztA_Thi, ztA_Tlo);

  dim3 g256(4, 4, 32);
  u16 *cN0 = ztA_Nhi, *cN1 = ztA_Nlo, *cT0 = ztA_Thi, *cT1 = ztA_Tlo;
  u16 *nN0 = ztB_Nhi, *nN1 = ztB_Nlo, *nT0 = ztB_Thi, *nT1 = ztB_Tlo;
  for (int it = 0; it < 6; ++it) {
    bool last = (it == 5);
    // NS self-corrects: bf16-level error entering the last full-precision
    // iteration is contracted cubically. NP=1 for it<5, NP=3 for it=5.
    if (it < 5) {
      k_nn_mfma<1><<<g256, 256, 0, stream>>>(aNhi, aNlo, cT0, cT1, az_Nhi, az_Nlo,
                                             az_Thi, az_Tlo, 256, 1.f, 0.f, 0.f);
      k_nn_mfma<1><<<g256, 256, 0, stream>>>(az_Nhi, az_Nlo, az_Thi, az_Tlo, nullptr,
                                             nullptr, taThi, taTlo, 256, 1.f, -7.f, 15.f);
      k_nn_mfma<1><<<g256, 256, 0, stream>>>(az_Nhi, az_Nlo, taThi, taTlo, nullptr,
                                             nullptr, tcThi, tcTlo, 256, -1.f, 0.f, 13.f);
      k_nn_mfma<1><<<g256, 256, 0, stream>>>(cN0, cN1, tcThi, tcTlo, nN0, nN1,
                                             nT0, nT1, 256, 0.25f, 0.f, 0.f);
    } else {
      k_nn_mfma<3><<<g256, 256, 0, stream>>>(aNhi, aNlo, cT0, cT1, az_Nhi, az_Nlo,
                                             az_Thi, az_Tlo, 256, 1.f, 0.f, 0.f);
      k_nn_mfma<3><<<g256, 256, 0, stream>>>(az_Nhi, az_Nlo, az_Thi, az_Tlo, nullptr,
                                             nullptr, taThi, taTlo, 256, 1.f, -7.f, 15.f);
      k_nn_mfma<3><<<g256, 256, 0, stream>>>(az_Nhi, az_Nlo, taThi, taTlo, nullptr,
                                             nullptr, tcThi, tcTlo, 256, -1.f, 0.f, 13.f);
      k_nn_mfma<3><<<g256, 256, 0, stream>>>(cN0, cN1, tcThi, tcTlo, nN0, nN1,
                                             last ? nullptr : nT0, last ? nullptr : nT1,
                                             256, 0.25f, 0.f, 0.f);
    }
    u16* t0;
    t0 = cN0; cN0 = nN0; nN0 = t0;  t0 = cN1; cN1 = nN1; nN1 = t0;
    t0 = cT0; cT0 = nT0; nT0 = t0;  t0 = cT1; cT1 = nT1; nT1 = t0;
  }
  // T2^T = (pinv @ T1)^T, plain bf16, [bh][64 dh][256 m] via CT store
  k_nn_mfma<3><<<dim3(1, 4, 32), 256, 0, stream>>>(cN0, cN1, T1thi, T1tlo, nullptr,
                                                   nullptr, T2t, nullptr, 64,
                                                   1.f, 0.f, 0.f);

  k_fused_attn1<<<dim3(128, 32), 256, 0, stream>>>(qb, klh, T2t, Ob);
  k_gemm128<2><<<dim3(4, 256), 256, 0, stream>>>(Ob, wot, out, nullptr, x, bo, 512);
}